// Round 2
// 1764.146 us; speedup vs baseline: 1.0825x; 1.0825x over previous
//
#include <hip/hip_runtime.h>
#include <cstdint>
#include <cstddef>

#define B_  256
#define N_  128
#define D_  1024
#define H_  4096
#define K1_ 819
#define K2_ 3276
#define K1P 832      // 26 * 32
#define K2P 3296     // 103 * 32
#define KT1 (K1P / 32)
#define KT2 (K2P / 32)

typedef __bf16 bf16x8 __attribute__((ext_vector_type(8)));
typedef float floatx4 __attribute__((ext_vector_type(4)));

__device__ __forceinline__ unsigned short f2bf(float f) {
  unsigned u = __float_as_uint(f);
  u += 0x7FFFu + ((u >> 16) & 1u);   // RNE
  return (unsigned short)(u >> 16);
}
__device__ __forceinline__ float bf2f(unsigned short s) {
  return __uint_as_float(((unsigned)s) << 16);
}

// async global->LDS, 16B per lane; lds dest is wave-uniform base + lane*16
#define GL16(gp, lp) __builtin_amdgcn_global_load_lds( \
    (const __attribute__((address_space(1))) void*)(gp), \
    (__attribute__((address_space(3))) void*)(lp), 16, 0, 0)

// ---------------------------------------------------------------------------
// scores1[b,c] = sum_n x[b,n,c] * ws1[n], fp64 accumulate (selection-critical)
// ---------------------------------------------------------------------------
__global__ __launch_bounds__(256) void scores1_kernel(const float* __restrict__ x,
                                                      const float* __restrict__ ws1,
                                                      float* __restrict__ scores1) {
  int b = blockIdx.x, t = threadIdx.x;
  __shared__ float w[N_];
  if (t < N_) w[t] = ws1[t];
  __syncthreads();
  const float* xb = x + (size_t)b * N_ * D_;
  double a0 = 0, a1 = 0, a2 = 0, a3 = 0;
  for (int n = 0; n < N_; ++n) {
    double wv = (double)w[n];
    const float* r = xb + (size_t)n * D_ + t;
    a0 += (double)r[0]   * wv;
    a1 += (double)r[256] * wv;
    a2 += (double)r[512] * wv;
    a3 += (double)r[768] * wv;
  }
  float* s = scores1 + (size_t)b * D_ + t;
  s[0]   = (float)a0;
  s[256] = (float)a1;
  s[512] = (float)a2;
  s[768] = (float)a3;
}

// ---------------------------------------------------------------------------
// Exact top-K per row: 8-bit radix select + index-ordered compaction.
// ---------------------------------------------------------------------------
__global__ __launch_bounds__(256) void topk_kernel(const float* __restrict__ scores,
                                                   int C, int K,
                                                   int* __restrict__ idx_out) {
  int b = blockIdx.x, t = threadIdx.x;
  __shared__ unsigned keys[4096];
  __shared__ unsigned hist[256];
  __shared__ unsigned sbuf[256];
  __shared__ unsigned s_sel, s_want, s_bgt, s_beq;

  for (int c = t; c < C; c += 256) {
    unsigned u = __float_as_uint(scores[(size_t)b * C + c]);
    keys[c] = u ^ ((u & 0x80000000u) ? 0xFFFFFFFFu : 0x80000000u);
  }
  if (t == 0) { s_want = (unsigned)K; s_bgt = 0u; s_beq = 0u; }
  __syncthreads();

  unsigned prefix = 0;
  for (int shift = 24; shift >= 0; shift -= 8) {
    hist[t] = 0u;
    __syncthreads();
    unsigned mask = (shift == 24) ? 0u : (0xFFFFFFFFu << (shift + 8));
    for (int c = t; c < C; c += 256) {
      unsigned k = keys[c];
      if ((k & mask) == (prefix & mask))
        atomicAdd(&hist[(k >> shift) & 0xFFu], 1u);
    }
    __syncthreads();
    if (t == 0) {
      unsigned want = s_want, cum = 0u, sel = 0u;
      for (int d = 255; d >= 0; --d) {
        cum += hist[d];
        if (cum >= want) { sel = (unsigned)d; s_want = want - (cum - hist[d]); break; }
      }
      s_sel = sel;
    }
    __syncthreads();
    prefix |= (s_sel << shift);
  }
  unsigned kth = prefix;
  unsigned n_eq_keep = s_want;
  __syncthreads();

  int nch = C >> 8;
  for (int ch = 0; ch < nch; ++ch) {
    int c = (ch << 8) + t;
    unsigned k = keys[c];
    unsigned gt = (k > kth) ? 1u : 0u;
    unsigned eq = (k == kth) ? 1u : 0u;
    unsigned val = gt | (eq << 16);
    sbuf[t] = val;
    __syncthreads();
    unsigned incl = val;
    for (int off = 1; off < 256; off <<= 1) {
      unsigned o = (t >= off) ? sbuf[t - off] : 0u;
      __syncthreads();
      incl += o;
      sbuf[t] = incl;
      __syncthreads();
    }
    unsigned excl = incl - val;
    unsigned gt_ex = excl & 0xFFFFu, eq_ex = excl >> 16;
    unsigned base_gt = s_bgt, base_eq = s_beq;
    unsigned eq_before = base_eq + eq_ex;
    bool keep = (gt != 0u) || ((eq != 0u) && (eq_before < n_eq_keep));
    unsigned kept_eq_before = (eq_before < n_eq_keep) ? eq_before : n_eq_keep;
    unsigned pos = base_gt + gt_ex + kept_eq_before;
    if (keep) idx_out[(size_t)b * K + pos] = c;
    __syncthreads();
    if (t == 255) {
      s_bgt = base_gt + (incl & 0xFFFFu);
      s_beq = base_eq + (incl >> 16);
    }
    __syncthreads();
  }
}

// ---------------------------------------------------------------------------
// Prep: gather + hi/lo bf16 split of x into xch/xcl [B][N][K1P]
// ---------------------------------------------------------------------------
__global__ __launch_bounds__(256) void xprep_kernel(const float* __restrict__ x,
                                                    const int* __restrict__ idx1,
                                                    unsigned short* __restrict__ xch,
                                                    unsigned short* __restrict__ xcl) {
  int bn = blockIdx.x;
  int b = bn >> 7;
  const int* idxb = idx1 + (size_t)b * K1_;
  const float* xr = x + (size_t)bn * D_;
  unsigned short* oh = xch + (size_t)bn * K1P;
  unsigned short* ol = xcl + (size_t)bn * K1P;
  for (int j = threadIdx.x; j < K1P; j += 256) {
    float v = (j < K1_) ? xr[idxb[j]] : 0.f;
    unsigned short hi = f2bf(v);
    unsigned short lo = f2bf(v - bf2f(hi));
    oh[j] = hi;
    ol[j] = lo;
  }
}

// hi/lo split of W1 [H][K1] -> [H][K1P]
__global__ __launch_bounds__(256) void w1split_kernel(const float* __restrict__ W1,
                                                      unsigned short* __restrict__ w1h,
                                                      unsigned short* __restrict__ w1l) {
  int e = blockIdx.x * 256 + threadIdx.x;
  int k = e % K1P, row = e / K1P;
  float v = (k < K1_) ? W1[(size_t)row * K1_ + k] : 0.f;
  unsigned short hi = f2bf(v);
  unsigned short lo = f2bf(v - bf2f(hi));
  w1h[e] = hi;
  w1l[e] = lo;
}

// bf16 convert of W2 [D][K2] -> [D][K2P]
__global__ __launch_bounds__(256) void w2conv_kernel(const float* __restrict__ W2,
                                                     unsigned short* __restrict__ w2b) {
  int e = blockIdx.x * 256 + threadIdx.x;
  int k = e % K2P, row = e / K2P;
  w2b[e] = (k < K2_) ? f2bf(W2[(size_t)row * K2_ + k]) : (unsigned short)0;
}

// gather h [B][N][H] bf16 -> hcomp [B][N][K2P] bf16
__global__ __launch_bounds__(256) void hcompact_kernel(const unsigned short* __restrict__ h,
                                                       const int* __restrict__ idx2,
                                                       unsigned short* __restrict__ hcomp) {
  int bn = blockIdx.x;
  int b = bn >> 7;
  const int* idxb = idx2 + (size_t)b * K2_;
  const unsigned short* hr = h + (size_t)bn * H_;
  unsigned short* o = hcomp + (size_t)bn * K2P;
  for (int j = threadIdx.x; j < K2P; j += 256)
    o[j] = (j < K2_) ? hr[idxb[j]] : (unsigned short)0;
}

// ---------------------------------------------------------------------------
// GEMM1: h = relu(xc * W1^T + b1) via bf16x3 split MFMA; bf16 h store + fused
// scores2 epilogue.
// Structure: 256(n: 2 batches x 128) x 256(hc) tile, 8 waves (2x4),
// BK=32, double-buffered LDS (exactly 128 KiB), 4 phases/K-tile with counted
// vmcnt (never drained to 0 in main loop), raw s_barrier, setprio around MFMA.
// LDS chunk c (16B) <-> row=((c>>6)<<4)|(c&15), kofs=((c>>4)&3)*8 (frag-order,
// conflict-free; GL16 dest stays linear).
// ---------------------------------------------------------------------------
#define MF1(d, a, b) d = __builtin_amdgcn_mfma_f32_16x16x32_bf16(a, b, d, 0, 0, 0)

// lgkm drain + 24-MFMA cluster for rows i0,i0+1 (3-pass split), then barrier
#define CLUSTER24(i0, A0H, A0L, A1H, A1L) \
  asm volatile("s_waitcnt lgkmcnt(0)" ::: "memory"); \
  __builtin_amdgcn_sched_barrier(0); \
  __builtin_amdgcn_s_setprio(1); \
  { _Pragma("unroll") \
    for (int j = 0; j < 4; ++j) { \
      MF1(acc[i0][j], A0H, bh[j]); \
      MF1(acc[i0][j], A0H, bl[j]); \
      MF1(acc[i0][j], A0L, bh[j]); \
      MF1(acc[(i0) + 1][j], A1H, bh[j]); \
      MF1(acc[(i0) + 1][j], A1H, bl[j]); \
      MF1(acc[(i0) + 1][j], A1L, bh[j]); \
    } } \
  __builtin_amdgcn_s_setprio(0); \
  __builtin_amdgcn_s_barrier();

// mid phase: read A-frag pair, issue one prefetch pair, barrier, cluster
#define PHASE_MID(i0, SRC0, DST0, SRC1, DST1) \
  { bf16x8 p0h = *(const bf16x8*)&Ah[cur][aof(i0)]; \
    bf16x8 p0l = *(const bf16x8*)&Al[cur][aof(i0)]; \
    bf16x8 p1h = *(const bf16x8*)&Ah[cur][aof((i0) + 1)]; \
    bf16x8 p1l = *(const bf16x8*)&Al[cur][aof((i0) + 1)]; \
    if (stg) { GL16(SRC0, DST0); GL16(SRC1, DST1); } \
    __builtin_amdgcn_s_barrier(); \
    CLUSTER24(i0, p0h, p0l, p1h, p1l) }

__global__ __launch_bounds__(512, 2) void gemm1_kernel(
    const unsigned short* __restrict__ xch, const unsigned short* __restrict__ xcl,
    const unsigned short* __restrict__ w1h, const unsigned short* __restrict__ w1l,
    const float* __restrict__ b1, const float* __restrict__ ws2,
    unsigned short* __restrict__ h, float* __restrict__ scores2) {
  const int hc0 = blockIdx.x * 256;
  const int b0 = blockIdx.y * 2;
  const int t = threadIdx.x, w = t >> 6, lane = t & 63;
  const int ml = lane & 15, qd = lane >> 4;
  const int wm = w >> 2, wn = w & 3;   // 2(m) x 4(n) wave grid

  // exactly 128 KiB of LDS (proven footprint); ws2 is read from global in
  // the epilogue (128 floats, L1-resident) to stay at 131072 bytes.
  __shared__ unsigned short Ah[2][8192], Al[2][8192], Bh[2][8192], Bl[2][8192];

  floatx4 acc[8][4] = {};

  const unsigned short* Abh = xch + (size_t)b0 * N_ * K1P;   // 256 rows (2 batches)
  const unsigned short* Abl = xcl + (size_t)b0 * N_ * K1P;
  const unsigned short* Bbh = w1h + (size_t)hc0 * K1P;       // 256 hc rows
  const unsigned short* Bbl = w1l + (size_t)hc0 * K1P;

  // GL16 statement s in {0,1}: chunk c = s*512 + w*64 + lane
  const int c0 = w * 64 + lane, c1 = c0 + 512;
  const size_t off0 = (size_t)(((c0 >> 6) << 4) | (c0 & 15)) * K1P + (size_t)(((c0 >> 4) & 3) * 8);
  const size_t off1 = (size_t)(((c1 >> 6) << 4) | (c1 & 15)) * K1P + (size_t)(((c1 >> 4) & 3) * 8);
  const int lb0 = (w * 64) * 8;          // ushort offset, wave-uniform dest, stmt 0
  const int lb1 = (512 + w * 64) * 8;    // stmt 1

  auto aof = [&](int i) { return ((wm * 8 + i) * 64 + qd * 16 + ml) * 8; };

  // prologue: fully stage K-tile 0 into buffer 0 (8 loads/wave)
  GL16(Abh + off0, &Ah[0][lb0]); GL16(Abh + off1, &Ah[0][lb1]);
  GL16(Abl + off0, &Al[0][lb0]); GL16(Abl + off1, &Al[0][lb1]);
  GL16(Bbh + off0, &Bh[0][lb0]); GL16(Bbh + off1, &Bh[0][lb1]);
  GL16(Bbl + off0, &Bl[0][lb0]); GL16(Bbl + off1, &Bl[0][lb1]);

  for (int kt = 0; kt < KT1; ++kt) {
    const int cur = kt & 1, nxt = cur ^ 1;
    const size_t kk = (size_t)(kt + 1) * 32;
    const bool stg = (kt + 1 < KT1);

    // ---- phase 0: prefetch Bh pair, counted-vmcnt wait for cur, read B + A0/A1
    if (stg) { GL16(Bbh + off0 + kk, &Bh[nxt][lb0]); GL16(Bbh + off1 + kk, &Bh[nxt][lb1]); }
    if (stg) asm volatile("s_waitcnt vmcnt(2)" ::: "memory");
    else     asm volatile("s_waitcnt vmcnt(0)" ::: "memory");
    __builtin_amdgcn_s_barrier();
    __builtin_amdgcn_sched_barrier(0);
    bf16x8 bh[4], bl[4];
#pragma unroll
    for (int j = 0; j < 4; ++j) {
      const int bo = ((wn * 4 + j) * 64 + qd * 16 + ml) * 8;
      bh[j] = *(const bf16x8*)&Bh[cur][bo];
      bl[j] = *(const bf16x8*)&Bl[cur][bo];
    }
    {
      bf16x8 p0h = *(const bf16x8*)&Ah[cur][aof(0)];
      bf16x8 p0l = *(const bf16x8*)&Al[cur][aof(0)];
      bf16x8 p1h = *(const bf16x8*)&Ah[cur][aof(1)];
      bf16x8 p1l = *(const bf16x8*)&Al[cur][aof(1)];
      CLUSTER24(0, p0h, p0l, p1h, p1l)
    }
    // ---- phases 1..3: read next A-frag pair, issue one prefetch pair each
    PHASE_MID(2, Bbl + off0 + kk, &Bl[nxt][lb0], Bbl + off1 + kk, &Bl[nxt][lb1])
    PHASE_MID(4, Abh + off0 + kk, &Ah[nxt][lb0], Abh + off1 + kk, &Ah[nxt][lb1])
    PHASE_MID(6, Abl + off0 + kk, &Al[nxt][lb0], Abl + off1 + kk, &Al[nxt][lb1])
  }

  // epilogue: bias+relu, bf16 h store, scores2 (each wave owns one full batch
  // row-range -> intra-wave shuffle reduce only, no LDS reduction needed)
  const int bb = b0 + wm;
  float bias[4];
#pragma unroll
  for (int j = 0; j < 4; ++j) bias[j] = b1[hc0 + wn * 64 + j * 16 + ml];
  float sc[4] = {0.f, 0.f, 0.f, 0.f};
#pragma unroll
  for (int i = 0; i < 8; ++i) {
#pragma unroll
    for (int r = 0; r < 4; ++r) {
      const int n = i * 16 + qd * 4 + r;
      const float wsn = ws2[n];
      unsigned short* hp = h + ((size_t)(bb * N_ + n)) * H_ + hc0 + wn * 64;
#pragma unroll
      for (int j = 0; j < 4; ++j) {
        float v = acc[i][j][r] + bias[j];
        v = fmaxf(v, 0.f);
        hp[j * 16 + ml] = f2bf(v);
        sc[j] += v * wsn;
      }
    }
  }
#pragma unroll
  for (int j = 0; j < 4; ++j) {
    sc[j] += __shfl_xor(sc[j], 16);
    sc[j] += __shfl_xor(sc[j], 32);
  }
  if (lane < 16) {
#pragma unroll
    for (int j = 0; j < 4; ++j)
      scores2[(size_t)bb * H_ + hc0 + wn * 64 + j * 16 + lane] = sc[j];
  }
}

// ---------------------------------------------------------------------------
// GEMM2: out = hcomp * W2^T + b2, single bf16 MFMA, fp32 out.
// ---------------------------------------------------------------------------
__global__ __launch_bounds__(256) void gemm2_kernel(
    const unsigned short* __restrict__ hcomp, const unsigned short* __restrict__ w2b,
    const float* __restrict__ b2, float* __restrict__ out) {
  const int b = blockIdx.y, d0 = blockIdx.x * 128;
  const int t = threadIdx.x, w = t >> 6, lane = t & 63;
  const int ml = lane & 15, qd = lane >> 4;
  __shared__ unsigned short Ah[4096], Bh[4096];

  floatx4 acc[4][4] = {};

  const unsigned short* Ab = hcomp + (size_t)b * N_ * K2P;
  const unsigned short* Bb = w2b + (size_t)d0 * K2P;

  const int c0 = w * 64 + lane, c1 = c0 + 256;
  const size_t off0 = (size_t)(((c0 >> 6) << 4) | (c0 & 15)) * K2P + (size_t)(((c0 >> 4) & 3) * 8);
  const size_t off1 = (size_t)(((c1 >> 6) << 4) | (c1 & 15)) * K2P + (size_t)(((c1 >> 4) & 3) * 8);
  const int lb0 = w * 512, lb1 = 2048 + w * 512;

  int aoff[4], boff[4];
#pragma unroll
  for (int i = 0; i < 4; ++i) {
    aoff[i] = ((((w >> 1) * 4 + i) * 64) + qd * 16 + ml) * 8;
    boff[i] = ((((w & 1) * 4 + i) * 64) + qd * 16 + ml) * 8;
  }

  for (int kt = 0; kt < KT2; ++kt) {
    const int k0 = kt * 32;
    __syncthreads();
    GL16(Ab + off0 + k0, &Ah[lb0]);
    GL16(Ab + off1 + k0, &Ah[lb1]);
    GL16(Bb + off0 + k0, &Bh[lb0]);
    GL16(Bb + off1 + k0, &Bh[lb1]);
    __syncthreads();
    bf16x8 ah[4];
#pragma unroll
    for (int i = 0; i < 4; ++i) ah[i] = *(const bf16x8*)&Ah[aoff[i]];
#pragma unroll
    for (int j = 0; j < 4; ++j) {
      const bf16x8 bh = *(const bf16x8*)&Bh[boff[j]];
#pragma unroll
      for (int i = 0; i < 4; ++i)
        acc[i][j] = __builtin_amdgcn_mfma_f32_16x16x32_bf16(ah[i], bh, acc[i][j], 0, 0, 0);
    }
  }

  const int wr0 = (w >> 1) * 64, wc0 = (w & 1) * 64;
  float bias[4];
#pragma unroll
  for (int j = 0; j < 4; ++j) bias[j] = b2[d0 + wc0 + j * 16 + ml];
#pragma unroll
  for (int i = 0; i < 4; ++i) {
#pragma unroll
    for (int r = 0; r < 4; ++r) {
      const int n = wr0 + i * 16 + qd * 4 + r;
      float* op = out + ((size_t)(b * N_ + n)) * D_ + d0 + wc0;
#pragma unroll
      for (int j = 0; j < 4; ++j)
        op[j * 16 + ml] = acc[i][j][r] + bias[j];
    }
  }
}

// ---------------------------------------------------------------------------
extern "C" void kernel_launch(void* const* d_in, const int* in_sizes, int n_in,
                              void* d_out, int out_size, void* d_ws, size_t ws_size,
                              hipStream_t stream) {
  (void)in_sizes; (void)n_in; (void)out_size; (void)ws_size;
  const float* x   = (const float*)d_in[0];
  const float* ws1 = (const float*)d_in[1];
  const float* W1  = (const float*)d_in[3];
  const float* b1  = (const float*)d_in[4];
  const float* ws2 = (const float*)d_in[5];
  const float* W2  = (const float*)d_in[7];
  const float* b2  = (const float*)d_in[8];
  float* out = (float*)d_out;

  char* p = (char*)d_ws;
  auto alloc = [&](size_t bytes) {
    char* r = p;
    p += (bytes + 255) & ~(size_t)255;
    return r;
  };
  float* scores1 = (float*)alloc((size_t)B_ * D_ * sizeof(float));
  int*   idx1    = (int*)  alloc((size_t)B_ * K1_ * sizeof(int));
  float* scores2 = (float*)alloc((size_t)B_ * H_ * sizeof(float));
  int*   idx2    = (int*)  alloc((size_t)B_ * K2_ * sizeof(int));
  unsigned short* w1h = (unsigned short*)alloc((size_t)H_ * K1P * sizeof(short));
  unsigned short* w1l = (unsigned short*)alloc((size_t)H_ * K1P * sizeof(short));
  unsigned short* w2b = (unsigned short*)alloc((size_t)D_ * K2P * sizeof(short));
  unsigned short* h   = (unsigned short*)alloc((size_t)B_ * N_ * H_ * sizeof(short));
  // region shared by {xch, xcl} (live through gemm1) and hcomp (live after)
  size_t xc_bytes    = (size_t)B_ * N_ * K1P * sizeof(short);   // 54.5 MB each
  size_t hcomp_bytes = (size_t)B_ * N_ * K2P * sizeof(short);   // 216 MB
  char* region = alloc(hcomp_bytes > 2 * xc_bytes ? hcomp_bytes : 2 * xc_bytes);
  unsigned short* xch   = (unsigned short*)region;
  unsigned short* xcl   = (unsigned short*)(region + xc_bytes);
  unsigned short* hcomp = (unsigned short*)region;  // aliases xc after gemm1 (stream-ordered)

  scores1_kernel<<<B_, 256, 0, stream>>>(x, ws1, scores1);
  topk_kernel<<<B_, 256, 0, stream>>>(scores1, D_, K1_, idx1);
  xprep_kernel<<<B_ * N_, 256, 0, stream>>>(x, idx1, xch, xcl);
  w1split_kernel<<<(H_ * K1P) / 256, 256, 0, stream>>>(W1, w1h, w1l);
  w2conv_kernel<<<(D_ * K2P) / 256, 256, 0, stream>>>(W2, w2b);
  gemm1_kernel<<<dim3(H_ / 256, B_ / 2), 512, 0, stream>>>(xch, xcl, w1h, w1l, b1, ws2, h, scores2);
  topk_kernel<<<B_, 256, 0, stream>>>(scores2, H_, K2_, idx2);
  hcompact_kernel<<<B_ * N_, 256, 0, stream>>>(h, idx2, hcomp);
  gemm2_kernel<<<dim3(D_ / 128, B_), 256, 0, stream>>>(hcomp, w2b, b2, out);
}

// Round 3
// 1728.317 us; speedup vs baseline: 1.1049x; 1.0207x over previous
//
#include <hip/hip_runtime.h>
#include <cstdint>
#include <cstddef>

#define B_  256
#define N_  128
#define D_  1024
#define H_  4096
#define K1_ 819
#define K2_ 3276
#define K1P 832      // 26 * 32
#define K2P 3296     // 103 * 32
#define KT1 (K1P / 32)
#define KT2 (K2P / 32)

typedef __bf16 bf16x8 __attribute__((ext_vector_type(8)));
typedef float floatx4 __attribute__((ext_vector_type(4)));

__device__ __forceinline__ unsigned short f2bf(float f) {
  unsigned u = __float_as_uint(f);
  u += 0x7FFFu + ((u >> 16) & 1u);   // RNE
  return (unsigned short)(u >> 16);
}
__device__ __forceinline__ float bf2f(unsigned short s) {
  return __uint_as_float(((unsigned)s) << 16);
}

// async global->LDS, 16B per lane; lds dest is wave-uniform base + lane*16
#define GL16(gp, lp) __builtin_amdgcn_global_load_lds( \
    (const __attribute__((address_space(1))) void*)(gp), \
    (__attribute__((address_space(3))) void*)(lp), 16, 0, 0)

// ---------------------------------------------------------------------------
// scores1[b,c] = sum_n x[b,n,c] * ws1[n], fp64 accumulate (selection-critical)
// ---------------------------------------------------------------------------
__global__ __launch_bounds__(256) void scores1_kernel(const float* __restrict__ x,
                                                      const float* __restrict__ ws1,
                                                      float* __restrict__ scores1) {
  int b = blockIdx.x, t = threadIdx.x;
  __shared__ float w[N_];
  if (t < N_) w[t] = ws1[t];
  __syncthreads();
  const float* xb = x + (size_t)b * N_ * D_;
  double a0 = 0, a1 = 0, a2 = 0, a3 = 0;
  for (int n = 0; n < N_; ++n) {
    double wv = (double)w[n];
    const float* r = xb + (size_t)n * D_ + t;
    a0 += (double)r[0]   * wv;
    a1 += (double)r[256] * wv;
    a2 += (double)r[512] * wv;
    a3 += (double)r[768] * wv;
  }
  float* s = scores1 + (size_t)b * D_ + t;
  s[0]   = (float)a0;
  s[256] = (float)a1;
  s[512] = (float)a2;
  s[768] = (float)a3;
}

// ---------------------------------------------------------------------------
// Exact top-K per row: 8-bit radix select + index-ordered compaction.
// ---------------------------------------------------------------------------
__global__ __launch_bounds__(256) void topk_kernel(const float* __restrict__ scores,
                                                   int C, int K,
                                                   int* __restrict__ idx_out) {
  int b = blockIdx.x, t = threadIdx.x;
  __shared__ unsigned keys[4096];
  __shared__ unsigned hist[256];
  __shared__ unsigned sbuf[256];
  __shared__ unsigned s_sel, s_want, s_bgt, s_beq;

  for (int c = t; c < C; c += 256) {
    unsigned u = __float_as_uint(scores[(size_t)b * C + c]);
    keys[c] = u ^ ((u & 0x80000000u) ? 0xFFFFFFFFu : 0x80000000u);
  }
  if (t == 0) { s_want = (unsigned)K; s_bgt = 0u; s_beq = 0u; }
  __syncthreads();

  unsigned prefix = 0;
  for (int shift = 24; shift >= 0; shift -= 8) {
    hist[t] = 0u;
    __syncthreads();
    unsigned mask = (shift == 24) ? 0u : (0xFFFFFFFFu << (shift + 8));
    for (int c = t; c < C; c += 256) {
      unsigned k = keys[c];
      if ((k & mask) == (prefix & mask))
        atomicAdd(&hist[(k >> shift) & 0xFFu], 1u);
    }
    __syncthreads();
    if (t == 0) {
      unsigned want = s_want, cum = 0u, sel = 0u;
      for (int d = 255; d >= 0; --d) {
        cum += hist[d];
        if (cum >= want) { sel = (unsigned)d; s_want = want - (cum - hist[d]); break; }
      }
      s_sel = sel;
    }
    __syncthreads();
    prefix |= (s_sel << shift);
  }
  unsigned kth = prefix;
  unsigned n_eq_keep = s_want;
  __syncthreads();

  int nch = C >> 8;
  for (int ch = 0; ch < nch; ++ch) {
    int c = (ch << 8) + t;
    unsigned k = keys[c];
    unsigned gt = (k > kth) ? 1u : 0u;
    unsigned eq = (k == kth) ? 1u : 0u;
    unsigned val = gt | (eq << 16);
    sbuf[t] = val;
    __syncthreads();
    unsigned incl = val;
    for (int off = 1; off < 256; off <<= 1) {
      unsigned o = (t >= off) ? sbuf[t - off] : 0u;
      __syncthreads();
      incl += o;
      sbuf[t] = incl;
      __syncthreads();
    }
    unsigned excl = incl - val;
    unsigned gt_ex = excl & 0xFFFFu, eq_ex = excl >> 16;
    unsigned base_gt = s_bgt, base_eq = s_beq;
    unsigned eq_before = base_eq + eq_ex;
    bool keep = (gt != 0u) || ((eq != 0u) && (eq_before < n_eq_keep));
    unsigned kept_eq_before = (eq_before < n_eq_keep) ? eq_before : n_eq_keep;
    unsigned pos = base_gt + gt_ex + kept_eq_before;
    if (keep) idx_out[(size_t)b * K + pos] = c;
    __syncthreads();
    if (t == 255) {
      s_bgt = base_gt + (incl & 0xFFFFu);
      s_beq = base_eq + (incl >> 16);
    }
    __syncthreads();
  }
}

// ---------------------------------------------------------------------------
// Prep: gather + hi/lo bf16 split of x into xch/xcl [B][N][K1P]
// ---------------------------------------------------------------------------
__global__ __launch_bounds__(256) void xprep_kernel(const float* __restrict__ x,
                                                    const int* __restrict__ idx1,
                                                    unsigned short* __restrict__ xch,
                                                    unsigned short* __restrict__ xcl) {
  int bn = blockIdx.x;
  int b = bn >> 7;
  const int* idxb = idx1 + (size_t)b * K1_;
  const float* xr = x + (size_t)bn * D_;
  unsigned short* oh = xch + (size_t)bn * K1P;
  unsigned short* ol = xcl + (size_t)bn * K1P;
  for (int j = threadIdx.x; j < K1P; j += 256) {
    float v = (j < K1_) ? xr[idxb[j]] : 0.f;
    unsigned short hi = f2bf(v);
    unsigned short lo = f2bf(v - bf2f(hi));
    oh[j] = hi;
    ol[j] = lo;
  }
}

// hi/lo split of W1 [H][K1] -> [H][K1P]
__global__ __launch_bounds__(256) void w1split_kernel(const float* __restrict__ W1,
                                                      unsigned short* __restrict__ w1h,
                                                      unsigned short* __restrict__ w1l) {
  int e = blockIdx.x * 256 + threadIdx.x;
  int k = e % K1P, row = e / K1P;
  float v = (k < K1_) ? W1[(size_t)row * K1_ + k] : 0.f;
  unsigned short hi = f2bf(v);
  unsigned short lo = f2bf(v - bf2f(hi));
  w1h[e] = hi;
  w1l[e] = lo;
}

// bf16 convert of W2 [D][K2] -> [D][K2P]
__global__ __launch_bounds__(256) void w2conv_kernel(const float* __restrict__ W2,
                                                     unsigned short* __restrict__ w2b) {
  int e = blockIdx.x * 256 + threadIdx.x;
  int k = e % K2P, row = e / K2P;
  w2b[e] = (k < K2_) ? f2bf(W2[(size_t)row * K2_ + k]) : (unsigned short)0;
}

// gather h [B][N][H] bf16 -> hcomp [B][N][K2P] bf16
__global__ __launch_bounds__(256) void hcompact_kernel(const unsigned short* __restrict__ h,
                                                       const int* __restrict__ idx2,
                                                       unsigned short* __restrict__ hcomp) {
  int bn = blockIdx.x;
  int b = bn >> 7;
  const int* idxb = idx2 + (size_t)b * K2_;
  const unsigned short* hr = h + (size_t)bn * H_;
  unsigned short* o = hcomp + (size_t)bn * K2P;
  for (int j = threadIdx.x; j < K2P; j += 256)
    o[j] = (j < K2_) ? hr[idxb[j]] : (unsigned short)0;
}

// ---------------------------------------------------------------------------
// GEMM1: h = relu(xc * W1^T + b1) via bf16x3 split MFMA; bf16 h store + fused
// scores2 epilogue.
// Structure: 256(n: 2 batches x 128) x 256(hc) tile, 8 waves (2x4), BK=32,
// double-buffered LDS (exactly 128 KiB). Per K-tile: 4 windows, ONE barrier
// each; fragment ds_reads for cluster p+1 are issued BEFORE cluster p's MFMAs
// so the compiler's counted lgkmcnt keeps them in flight UNDER the MFMAs
// (ds_read || MFMA overlap — the round-2 version serialized them).
// Counted vmcnt(2) at K-tile boundary only; setprio(1) around MFMA clusters.
// LDS chunk c (16B) <-> row=((c>>6)<<4)|(c&15), kofs=((c>>4)&3)*8 (frag-order,
// conflict-free; GL16 dest stays linear).
// ---------------------------------------------------------------------------
#define MF1(d, a, b) d = __builtin_amdgcn_mfma_f32_16x16x32_bf16(a, b, d, 0, 0, 0)

// 24-MFMA cluster for acc rows i0,i0+1 (3-pass hi/lo split). Exact same MFMA
// order per acc element as previous versions -> h is bitwise identical.
#define CLUSTER24(i0, A0H, A0L, A1H, A1L) \
  __builtin_amdgcn_s_setprio(1); \
  { _Pragma("unroll") \
    for (int j = 0; j < 4; ++j) { \
      MF1(acc[i0][j], A0H, bh[j]); \
      MF1(acc[i0][j], A0H, bl[j]); \
      MF1(acc[i0][j], A0L, bh[j]); \
      MF1(acc[(i0) + 1][j], A1H, bh[j]); \
      MF1(acc[(i0) + 1][j], A1H, bl[j]); \
      MF1(acc[(i0) + 1][j], A1L, bh[j]); \
    } } \
  __builtin_amdgcn_s_setprio(0);

__global__ __launch_bounds__(512, 2) void gemm1_kernel(
    const unsigned short* __restrict__ xch, const unsigned short* __restrict__ xcl,
    const unsigned short* __restrict__ w1h, const unsigned short* __restrict__ w1l,
    const float* __restrict__ b1, const float* __restrict__ ws2,
    unsigned short* __restrict__ h, float* __restrict__ scores2) {
  const int hc0 = blockIdx.x * 256;
  const int b0 = blockIdx.y * 2;
  const int t = threadIdx.x, w = t >> 6, lane = t & 63;
  const int ml = lane & 15, qd = lane >> 4;
  const int wm = w >> 2, wn = w & 3;   // 2(m) x 4(n) wave grid

  // exactly 128 KiB of LDS (proven footprint)
  __shared__ unsigned short Ah[2][8192], Al[2][8192], Bh[2][8192], Bl[2][8192];

  floatx4 acc[8][4] = {};

  const unsigned short* Abh = xch + (size_t)b0 * N_ * K1P;   // 256 rows (2 batches)
  const unsigned short* Abl = xcl + (size_t)b0 * N_ * K1P;
  const unsigned short* Bbh = w1h + (size_t)hc0 * K1P;       // 256 hc rows
  const unsigned short* Bbl = w1l + (size_t)hc0 * K1P;

  // GL16 statement s in {0,1}: chunk c = s*512 + w*64 + lane
  const int c0 = w * 64 + lane, c1 = c0 + 512;
  const size_t off0 = (size_t)(((c0 >> 6) << 4) | (c0 & 15)) * K1P + (size_t)(((c0 >> 4) & 3) * 8);
  const size_t off1 = (size_t)(((c1 >> 6) << 4) | (c1 & 15)) * K1P + (size_t)(((c1 >> 4) & 3) * 8);
  const int lb0 = (w * 64) * 8;          // ushort offset, wave-uniform dest, stmt 0
  const int lb1 = (512 + w * 64) * 8;    // stmt 1

  auto aof = [&](int i) { return ((wm * 8 + i) * 64 + qd * 16 + ml) * 8; };

  // prologue: fully stage K-tile 0 into buffer 0 (8 loads/wave)
  GL16(Abh + off0, &Ah[0][lb0]); GL16(Abh + off1, &Ah[0][lb1]);
  GL16(Abl + off0, &Al[0][lb0]); GL16(Abl + off1, &Al[0][lb1]);
  GL16(Bbh + off0, &Bh[0][lb0]); GL16(Bbh + off1, &Bh[0][lb1]);
  GL16(Bbl + off0, &Bl[0][lb0]); GL16(Bbl + off1, &Bl[0][lb1]);

  for (int kt = 0; kt < KT1; ++kt) {
    const int cur = kt & 1, nxt = cur ^ 1;
    const size_t kk = (size_t)(kt + 1) * 32;
    const bool stg = (kt + 1 < KT1);

    // ---- K-tile boundary: prefetch Bh pair into nxt, counted wait for cur
    if (stg) { GL16(Bbh + off0 + kk, &Bh[nxt][lb0]); GL16(Bbh + off1 + kk, &Bh[nxt][lb1]); }
    if (stg) asm volatile("s_waitcnt vmcnt(2)" ::: "memory");
    else     asm volatile("s_waitcnt vmcnt(0)" ::: "memory");
    __builtin_amdgcn_s_barrier();

    // ---- W0: issue B frags + pair01 + pair23; stage Bl; MFMA c01 (pair23 in flight)
    bf16x8 bh[4], bl[4];
#pragma unroll
    for (int j = 0; j < 4; ++j) {
      const int bo = ((wn * 4 + j) * 64 + qd * 16 + ml) * 8;
      bh[j] = *(const bf16x8*)&Bh[cur][bo];
      bl[j] = *(const bf16x8*)&Bl[cur][bo];
    }
    bf16x8 a0h = *(const bf16x8*)&Ah[cur][aof(0)];
    bf16x8 a0l = *(const bf16x8*)&Al[cur][aof(0)];
    bf16x8 a1h = *(const bf16x8*)&Ah[cur][aof(1)];
    bf16x8 a1l = *(const bf16x8*)&Al[cur][aof(1)];
    bf16x8 a2h = *(const bf16x8*)&Ah[cur][aof(2)];
    bf16x8 a2l = *(const bf16x8*)&Al[cur][aof(2)];
    bf16x8 a3h = *(const bf16x8*)&Ah[cur][aof(3)];
    bf16x8 a3l = *(const bf16x8*)&Al[cur][aof(3)];
    if (stg) { GL16(Bbl + off0 + kk, &Bl[nxt][lb0]); GL16(Bbl + off1 + kk, &Bl[nxt][lb1]); }
    __builtin_amdgcn_sched_barrier(0);
    CLUSTER24(0, a0h, a0l, a1h, a1l)
    __builtin_amdgcn_s_barrier();

    // ---- W1: issue pair45; stage Ah; MFMA c23 (pair45 in flight)
    bf16x8 a4h = *(const bf16x8*)&Ah[cur][aof(4)];
    bf16x8 a4l = *(const bf16x8*)&Al[cur][aof(4)];
    bf16x8 a5h = *(const bf16x8*)&Ah[cur][aof(5)];
    bf16x8 a5l = *(const bf16x8*)&Al[cur][aof(5)];
    if (stg) { GL16(Abh + off0 + kk, &Ah[nxt][lb0]); GL16(Abh + off1 + kk, &Ah[nxt][lb1]); }
    __builtin_amdgcn_sched_barrier(0);
    CLUSTER24(2, a2h, a2l, a3h, a3l)
    __builtin_amdgcn_s_barrier();

    // ---- W2: issue pair67; stage Al; MFMA c45 (pair67 in flight)
    bf16x8 a6h = *(const bf16x8*)&Ah[cur][aof(6)];
    bf16x8 a6l = *(const bf16x8*)&Al[cur][aof(6)];
    bf16x8 a7h = *(const bf16x8*)&Ah[cur][aof(7)];
    bf16x8 a7l = *(const bf16x8*)&Al[cur][aof(7)];
    if (stg) { GL16(Abl + off0 + kk, &Al[nxt][lb0]); GL16(Abl + off1 + kk, &Al[nxt][lb1]); }
    __builtin_amdgcn_sched_barrier(0);
    CLUSTER24(4, a4h, a4l, a5h, a5l)
    __builtin_amdgcn_s_barrier();

    // ---- W3: MFMA c67; end barrier protects cur from next boundary's GL16 (WAR)
    __builtin_amdgcn_sched_barrier(0);
    CLUSTER24(6, a6h, a6l, a7h, a7l)
    __builtin_amdgcn_s_barrier();
  }

  // epilogue: bias+relu, bf16 h store, scores2 (each wave owns one full batch
  // row-range -> intra-wave shuffle reduce only, no LDS reduction needed)
  const int bb = b0 + wm;
  float bias[4];
#pragma unroll
  for (int j = 0; j < 4; ++j) bias[j] = b1[hc0 + wn * 64 + j * 16 + ml];
  float sc[4] = {0.f, 0.f, 0.f, 0.f};
#pragma unroll
  for (int i = 0; i < 8; ++i) {
#pragma unroll
    for (int r = 0; r < 4; ++r) {
      const int n = i * 16 + qd * 4 + r;
      const float wsn = ws2[n];
      unsigned short* hp = h + ((size_t)(bb * N_ + n)) * H_ + hc0 + wn * 64;
#pragma unroll
      for (int j = 0; j < 4; ++j) {
        float v = acc[i][j][r] + bias[j];
        v = fmaxf(v, 0.f);
        hp[j * 16 + ml] = f2bf(v);
        sc[j] += v * wsn;
      }
    }
  }
#pragma unroll
  for (int j = 0; j < 4; ++j) {
    sc[j] += __shfl_xor(sc[j], 16);
    sc[j] += __shfl_xor(sc[j], 32);
  }
  if (lane < 16) {
#pragma unroll
    for (int j = 0; j < 4; ++j)
      scores2[(size_t)bb * H_ + hc0 + wn * 64 + j * 16 + lane] = sc[j];
  }
}

// ---------------------------------------------------------------------------
// GEMM2: out = hcomp * W2^T + b2, single bf16 MFMA, fp32 out.
// ---------------------------------------------------------------------------
__global__ __launch_bounds__(256) void gemm2_kernel(
    const unsigned short* __restrict__ hcomp, const unsigned short* __restrict__ w2b,
    const float* __restrict__ b2, float* __restrict__ out) {
  const int b = blockIdx.y, d0 = blockIdx.x * 128;
  const int t = threadIdx.x, w = t >> 6, lane = t & 63;
  const int ml = lane & 15, qd = lane >> 4;
  __shared__ unsigned short Ah[4096], Bh[4096];

  floatx4 acc[4][4] = {};

  const unsigned short* Ab = hcomp + (size_t)b * N_ * K2P;
  const unsigned short* Bb = w2b + (size_t)d0 * K2P;

  const int c0 = w * 64 + lane, c1 = c0 + 256;
  const size_t off0 = (size_t)(((c0 >> 6) << 4) | (c0 & 15)) * K2P + (size_t)(((c0 >> 4) & 3) * 8);
  const size_t off1 = (size_t)(((c1 >> 6) << 4) | (c1 & 15)) * K2P + (size_t)(((c1 >> 4) & 3) * 8);
  const int lb0 = w * 512, lb1 = 2048 + w * 512;

  int aoff[4], boff[4];
#pragma unroll
  for (int i = 0; i < 4; ++i) {
    aoff[i] = ((((w >> 1) * 4 + i) * 64) + qd * 16 + ml) * 8;
    boff[i] = ((((w & 1) * 4 + i) * 64) + qd * 16 + ml) * 8;
  }

  for (int kt = 0; kt < KT2; ++kt) {
    const int k0 = kt * 32;
    __syncthreads();
    GL16(Ab + off0 + k0, &Ah[lb0]);
    GL16(Ab + off1 + k0, &Ah[lb1]);
    GL16(Bb + off0 + k0, &Bh[lb0]);
    GL16(Bb + off1 + k0, &Bh[lb1]);
    __syncthreads();
    bf16x8 ah[4];
#pragma unroll
    for (int i = 0; i < 4; ++i) ah[i] = *(const bf16x8*)&Ah[aoff[i]];
#pragma unroll
    for (int j = 0; j < 4; ++j) {
      const bf16x8 bh = *(const bf16x8*)&Bh[boff[j]];
#pragma unroll
      for (int i = 0; i < 4; ++i)
        acc[i][j] = __builtin_amdgcn_mfma_f32_16x16x32_bf16(ah[i], bh, acc[i][j], 0, 0, 0);
    }
  }

  const int wr0 = (w >> 1) * 64, wc0 = (w & 1) * 64;
  float bias[4];
#pragma unroll
  for (int j = 0; j < 4; ++j) bias[j] = b2[d0 + wc0 + j * 16 + ml];
#pragma unroll
  for (int i = 0; i < 4; ++i) {
#pragma unroll
    for (int r = 0; r < 4; ++r) {
      const int n = wr0 + i * 16 + qd * 4 + r;
      float* op = out + ((size_t)(b * N_ + n)) * D_ + d0 + wc0;
#pragma unroll
      for (int j = 0; j < 4; ++j)
        op[j * 16 + ml] = acc[i][j][r] + bias[j];
    }
  }
}

// ---------------------------------------------------------------------------
extern "C" void kernel_launch(void* const* d_in, const int* in_sizes, int n_in,
                              void* d_out, int out_size, void* d_ws, size_t ws_size,
                              hipStream_t stream) {
  (void)in_sizes; (void)n_in; (void)out_size; (void)ws_size;
  const float* x   = (const float*)d_in[0];
  const float* ws1 = (const float*)d_in[1];
  const float* W1  = (const float*)d_in[3];
  const float* b1  = (const float*)d_in[4];
  const float* ws2 = (const float*)d_in[5];
  const float* W2  = (const float*)d_in[7];
  const float* b2  = (const float*)d_in[8];
  float* out = (float*)d_out;

  char* p = (char*)d_ws;
  auto alloc = [&](size_t bytes) {
    char* r = p;
    p += (bytes + 255) & ~(size_t)255;
    return r;
  };
  float* scores1 = (float*)alloc((size_t)B_ * D_ * sizeof(float));
  int*   idx1    = (int*)  alloc((size_t)B_ * K1_ * sizeof(int));
  float* scores2 = (float*)alloc((size_t)B_ * H_ * sizeof(float));
  int*   idx2    = (int*)  alloc((size_t)B_ * K2_ * sizeof(int));
  unsigned short* w1h = (unsigned short*)alloc((size_t)H_ * K1P * sizeof(short));
  unsigned short* w1l = (unsigned short*)alloc((size_t)H_ * K1P * sizeof(short));
  unsigned short* w2b = (unsigned short*)alloc((size_t)D_ * K2P * sizeof(short));
  unsigned short* h   = (unsigned short*)alloc((size_t)B_ * N_ * H_ * sizeof(short));
  // region shared by {xch, xcl} (live through gemm1) and hcomp (live after)
  size_t xc_bytes    = (size_t)B_ * N_ * K1P * sizeof(short);   // 54.5 MB each
  size_t hcomp_bytes = (size_t)B_ * N_ * K2P * sizeof(short);   // 216 MB
  char* region = alloc(hcomp_bytes > 2 * xc_bytes ? hcomp_bytes : 2 * xc_bytes);
  unsigned short* xch   = (unsigned short*)region;
  unsigned short* xcl   = (unsigned short*)(region + xc_bytes);
  unsigned short* hcomp = (unsigned short*)region;  // aliases xc after gemm1 (stream-ordered)

  scores1_kernel<<<B_, 256, 0, stream>>>(x, ws1, scores1);
  topk_kernel<<<B_, 256, 0, stream>>>(scores1, D_, K1_, idx1);
  xprep_kernel<<<B_ * N_, 256, 0, stream>>>(x, idx1, xch, xcl);
  w1split_kernel<<<(H_ * K1P) / 256, 256, 0, stream>>>(W1, w1h, w1l);
  w2conv_kernel<<<(D_ * K2P) / 256, 256, 0, stream>>>(W2, w2b);
  gemm1_kernel<<<dim3(H_ / 256, B_ / 2), 512, 0, stream>>>(xch, xcl, w1h, w1l, b1, ws2, h, scores2);
  topk_kernel<<<B_, 256, 0, stream>>>(scores2, H_, K2_, idx2);
  hcompact_kernel<<<B_ * N_, 256, 0, stream>>>(h, idx2, hcomp);
  gemm2_kernel<<<dim3(D_ / 128, B_), 256, 0, stream>>>(hcomp, w2b, b2, out);
}

// Round 4
// 1650.036 us; speedup vs baseline: 1.1574x; 1.0474x over previous
//
#include <hip/hip_runtime.h>
#include <cstdint>
#include <cstddef>

#define B_  256
#define N_  128
#define D_  1024
#define H_  4096
#define K1_ 819
#define K2_ 3276
#define K1P 832      // 26 * 32
#define K2P 3296     // 103 * 32
#define KT1 (K1P / 32)
#define KT2 (K2P / 32)

typedef __bf16 bf16x8 __attribute__((ext_vector_type(8)));
typedef float floatx4 __attribute__((ext_vector_type(4)));

__device__ __forceinline__ unsigned short f2bf(float f) {
  unsigned u = __float_as_uint(f);
  u += 0x7FFFu + ((u >> 16) & 1u);   // RNE
  return (unsigned short)(u >> 16);
}
__device__ __forceinline__ float bf2f(unsigned short s) {
  return __uint_as_float(((unsigned)s) << 16);
}

// async global->LDS, 16B per lane; lds dest is wave-uniform base + lane*16
#define GL16(gp, lp) __builtin_amdgcn_global_load_lds( \
    (const __attribute__((address_space(1))) void*)(gp), \
    (__attribute__((address_space(3))) void*)(lp), 16, 0, 0)

// ---------------------------------------------------------------------------
// scores1[b,c] = sum_n x[b,n,c] * ws1[n], fp64 accumulate (selection-critical)
// ---------------------------------------------------------------------------
__global__ __launch_bounds__(256) void scores1_kernel(const float* __restrict__ x,
                                                      const float* __restrict__ ws1,
                                                      float* __restrict__ scores1) {
  int b = blockIdx.x, t = threadIdx.x;
  __shared__ float w[N_];
  if (t < N_) w[t] = ws1[t];
  __syncthreads();
  const float* xb = x + (size_t)b * N_ * D_;
  double a0 = 0, a1 = 0, a2 = 0, a3 = 0;
  for (int n = 0; n < N_; ++n) {
    double wv = (double)w[n];
    const float* r = xb + (size_t)n * D_ + t;
    a0 += (double)r[0]   * wv;
    a1 += (double)r[256] * wv;
    a2 += (double)r[512] * wv;
    a3 += (double)r[768] * wv;
  }
  float* s = scores1 + (size_t)b * D_ + t;
  s[0]   = (float)a0;
  s[256] = (float)a1;
  s[512] = (float)a2;
  s[768] = (float)a3;
}

// ---------------------------------------------------------------------------
// Exact top-K per row: 8-bit radix select + index-ordered compaction.
// ---------------------------------------------------------------------------
__global__ __launch_bounds__(256) void topk_kernel(const float* __restrict__ scores,
                                                   int C, int K,
                                                   int* __restrict__ idx_out) {
  int b = blockIdx.x, t = threadIdx.x;
  __shared__ unsigned keys[4096];
  __shared__ unsigned hist[256];
  __shared__ unsigned sbuf[256];
  __shared__ unsigned s_sel, s_want, s_bgt, s_beq;

  for (int c = t; c < C; c += 256) {
    unsigned u = __float_as_uint(scores[(size_t)b * C + c]);
    keys[c] = u ^ ((u & 0x80000000u) ? 0xFFFFFFFFu : 0x80000000u);
  }
  if (t == 0) { s_want = (unsigned)K; s_bgt = 0u; s_beq = 0u; }
  __syncthreads();

  unsigned prefix = 0;
  for (int shift = 24; shift >= 0; shift -= 8) {
    hist[t] = 0u;
    __syncthreads();
    unsigned mask = (shift == 24) ? 0u : (0xFFFFFFFFu << (shift + 8));
    for (int c = t; c < C; c += 256) {
      unsigned k = keys[c];
      if ((k & mask) == (prefix & mask))
        atomicAdd(&hist[(k >> shift) & 0xFFu], 1u);
    }
    __syncthreads();
    if (t == 0) {
      unsigned want = s_want, cum = 0u, sel = 0u;
      for (int d = 255; d >= 0; --d) {
        cum += hist[d];
        if (cum >= want) { sel = (unsigned)d; s_want = want - (cum - hist[d]); break; }
      }
      s_sel = sel;
    }
    __syncthreads();
    prefix |= (s_sel << shift);
  }
  unsigned kth = prefix;
  unsigned n_eq_keep = s_want;
  __syncthreads();

  int nch = C >> 8;
  for (int ch = 0; ch < nch; ++ch) {
    int c = (ch << 8) + t;
    unsigned k = keys[c];
    unsigned gt = (k > kth) ? 1u : 0u;
    unsigned eq = (k == kth) ? 1u : 0u;
    unsigned val = gt | (eq << 16);
    sbuf[t] = val;
    __syncthreads();
    unsigned incl = val;
    for (int off = 1; off < 256; off <<= 1) {
      unsigned o = (t >= off) ? sbuf[t - off] : 0u;
      __syncthreads();
      incl += o;
      sbuf[t] = incl;
      __syncthreads();
    }
    unsigned excl = incl - val;
    unsigned gt_ex = excl & 0xFFFFu, eq_ex = excl >> 16;
    unsigned base_gt = s_bgt, base_eq = s_beq;
    unsigned eq_before = base_eq + eq_ex;
    bool keep = (gt != 0u) || ((eq != 0u) && (eq_before < n_eq_keep));
    unsigned kept_eq_before = (eq_before < n_eq_keep) ? eq_before : n_eq_keep;
    unsigned pos = base_gt + gt_ex + kept_eq_before;
    if (keep) idx_out[(size_t)b * K + pos] = c;
    __syncthreads();
    if (t == 255) {
      s_bgt = base_gt + (incl & 0xFFFFu);
      s_beq = base_eq + (incl >> 16);
    }
    __syncthreads();
  }
}

// ---------------------------------------------------------------------------
// Prep: gather + hi/lo bf16 split of x into xch/xcl [B][N][K1P]
// ---------------------------------------------------------------------------
__global__ __launch_bounds__(256) void xprep_kernel(const float* __restrict__ x,
                                                    const int* __restrict__ idx1,
                                                    unsigned short* __restrict__ xch,
                                                    unsigned short* __restrict__ xcl) {
  int bn = blockIdx.x;
  int b = bn >> 7;
  const int* idxb = idx1 + (size_t)b * K1_;
  const float* xr = x + (size_t)bn * D_;
  unsigned short* oh = xch + (size_t)bn * K1P;
  unsigned short* ol = xcl + (size_t)bn * K1P;
  for (int j = threadIdx.x; j < K1P; j += 256) {
    float v = (j < K1_) ? xr[idxb[j]] : 0.f;
    unsigned short hi = f2bf(v);
    unsigned short lo = f2bf(v - bf2f(hi));
    oh[j] = hi;
    ol[j] = lo;
  }
}

// hi/lo split of W1 [H][K1] -> [H][K1P]
__global__ __launch_bounds__(256) void w1split_kernel(const float* __restrict__ W1,
                                                      unsigned short* __restrict__ w1h,
                                                      unsigned short* __restrict__ w1l) {
  int e = blockIdx.x * 256 + threadIdx.x;
  int k = e % K1P, row = e / K1P;
  float v = (k < K1_) ? W1[(size_t)row * K1_ + k] : 0.f;
  unsigned short hi = f2bf(v);
  unsigned short lo = f2bf(v - bf2f(hi));
  w1h[e] = hi;
  w1l[e] = lo;
}

// bf16 convert of W2 [D][K2] -> [D][K2P]
__global__ __launch_bounds__(256) void w2conv_kernel(const float* __restrict__ W2,
                                                     unsigned short* __restrict__ w2b) {
  int e = blockIdx.x * 256 + threadIdx.x;
  int k = e % K2P, row = e / K2P;
  w2b[e] = (k < K2_) ? f2bf(W2[(size_t)row * K2_ + k]) : (unsigned short)0;
}

// gather h [B][N][H] bf16 -> hcomp [B][N][K2P] bf16
__global__ __launch_bounds__(256) void hcompact_kernel(const unsigned short* __restrict__ h,
                                                       const int* __restrict__ idx2,
                                                       unsigned short* __restrict__ hcomp) {
  int bn = blockIdx.x;
  int b = bn >> 7;
  const int* idxb = idx2 + (size_t)b * K2_;
  const unsigned short* hr = h + (size_t)bn * H_;
  unsigned short* o = hcomp + (size_t)bn * K2P;
  for (int j = threadIdx.x; j < K2P; j += 256)
    o[j] = (j < K2_) ? hr[idxb[j]] : (unsigned short)0;
}

// ---------------------------------------------------------------------------
// GEMM1: h = relu(xc * W1^T + b1) via bf16x3 split MFMA; bf16 h store + fused
// scores2 epilogue.
// Structure: 256(n: 2 batches x 128) x 256(hc) tile, 8 waves (2x4), BK=32,
// double-buffered LDS (exactly 128 KiB). Per K-tile: 4 windows, ONE barrier
// each; fragment ds_reads for cluster p+1 are issued BEFORE cluster p's MFMAs
// so the compiler's counted lgkmcnt keeps them in flight UNDER the MFMAs.
// Counted vmcnt(2) at K-tile boundary only; setprio(1) around MFMA clusters.
// LDS chunk c (16B) <-> row=((c>>6)<<4)|(c&15), kofs=((c>>4)&3)*8 (frag-order,
// conflict-free; GL16 dest stays linear).
// ---------------------------------------------------------------------------
#define MF1(d, a, b) d = __builtin_amdgcn_mfma_f32_16x16x32_bf16(a, b, d, 0, 0, 0)

// 24-MFMA cluster for acc rows i0,i0+1 (3-pass hi/lo split). Exact same MFMA
// order per acc element as previous versions -> h is bitwise identical.
#define CLUSTER24(i0, A0H, A0L, A1H, A1L) \
  __builtin_amdgcn_s_setprio(1); \
  { _Pragma("unroll") \
    for (int j = 0; j < 4; ++j) { \
      MF1(acc[i0][j], A0H, bh[j]); \
      MF1(acc[i0][j], A0H, bl[j]); \
      MF1(acc[i0][j], A0L, bh[j]); \
      MF1(acc[(i0) + 1][j], A1H, bh[j]); \
      MF1(acc[(i0) + 1][j], A1H, bl[j]); \
      MF1(acc[(i0) + 1][j], A1L, bh[j]); \
    } } \
  __builtin_amdgcn_s_setprio(0);

__global__ __launch_bounds__(512, 2) void gemm1_kernel(
    const unsigned short* __restrict__ xch, const unsigned short* __restrict__ xcl,
    const unsigned short* __restrict__ w1h, const unsigned short* __restrict__ w1l,
    const float* __restrict__ b1, const float* __restrict__ ws2,
    unsigned short* __restrict__ h, float* __restrict__ scores2) {
  const int hc0 = blockIdx.x * 256;
  const int b0 = blockIdx.y * 2;
  const int t = threadIdx.x, w = t >> 6, lane = t & 63;
  const int ml = lane & 15, qd = lane >> 4;
  const int wm = w >> 2, wn = w & 3;   // 2(m) x 4(n) wave grid

  // exactly 128 KiB of LDS (proven footprint)
  __shared__ unsigned short Ah[2][8192], Al[2][8192], Bh[2][8192], Bl[2][8192];

  floatx4 acc[8][4] = {};

  const unsigned short* Abh = xch + (size_t)b0 * N_ * K1P;   // 256 rows (2 batches)
  const unsigned short* Abl = xcl + (size_t)b0 * N_ * K1P;
  const unsigned short* Bbh = w1h + (size_t)hc0 * K1P;       // 256 hc rows
  const unsigned short* Bbl = w1l + (size_t)hc0 * K1P;

  // GL16 statement s in {0,1}: chunk c = s*512 + w*64 + lane
  const int c0 = w * 64 + lane, c1 = c0 + 512;
  const size_t off0 = (size_t)(((c0 >> 6) << 4) | (c0 & 15)) * K1P + (size_t)(((c0 >> 4) & 3) * 8);
  const size_t off1 = (size_t)(((c1 >> 6) << 4) | (c1 & 15)) * K1P + (size_t)(((c1 >> 4) & 3) * 8);
  const int lb0 = (w * 64) * 8;          // ushort offset, wave-uniform dest, stmt 0
  const int lb1 = (512 + w * 64) * 8;    // stmt 1

  auto aof = [&](int i) { return ((wm * 8 + i) * 64 + qd * 16 + ml) * 8; };

  // prologue: fully stage K-tile 0 into buffer 0 (8 loads/wave)
  GL16(Abh + off0, &Ah[0][lb0]); GL16(Abh + off1, &Ah[0][lb1]);
  GL16(Abl + off0, &Al[0][lb0]); GL16(Abl + off1, &Al[0][lb1]);
  GL16(Bbh + off0, &Bh[0][lb0]); GL16(Bbh + off1, &Bh[0][lb1]);
  GL16(Bbl + off0, &Bl[0][lb0]); GL16(Bbl + off1, &Bl[0][lb1]);

  for (int kt = 0; kt < KT1; ++kt) {
    const int cur = kt & 1, nxt = cur ^ 1;
    const size_t kk = (size_t)(kt + 1) * 32;
    const bool stg = (kt + 1 < KT1);

    // ---- K-tile boundary: prefetch Bh pair into nxt, counted wait for cur
    if (stg) { GL16(Bbh + off0 + kk, &Bh[nxt][lb0]); GL16(Bbh + off1 + kk, &Bh[nxt][lb1]); }
    if (stg) asm volatile("s_waitcnt vmcnt(2)" ::: "memory");
    else     asm volatile("s_waitcnt vmcnt(0)" ::: "memory");
    __builtin_amdgcn_s_barrier();

    // ---- W0: issue B frags + pair01 + pair23; stage Bl; MFMA c01 (pair23 in flight)
    bf16x8 bh[4], bl[4];
#pragma unroll
    for (int j = 0; j < 4; ++j) {
      const int bo = ((wn * 4 + j) * 64 + qd * 16 + ml) * 8;
      bh[j] = *(const bf16x8*)&Bh[cur][bo];
      bl[j] = *(const bf16x8*)&Bl[cur][bo];
    }
    bf16x8 a0h = *(const bf16x8*)&Ah[cur][aof(0)];
    bf16x8 a0l = *(const bf16x8*)&Al[cur][aof(0)];
    bf16x8 a1h = *(const bf16x8*)&Ah[cur][aof(1)];
    bf16x8 a1l = *(const bf16x8*)&Al[cur][aof(1)];
    bf16x8 a2h = *(const bf16x8*)&Ah[cur][aof(2)];
    bf16x8 a2l = *(const bf16x8*)&Al[cur][aof(2)];
    bf16x8 a3h = *(const bf16x8*)&Ah[cur][aof(3)];
    bf16x8 a3l = *(const bf16x8*)&Al[cur][aof(3)];
    if (stg) { GL16(Bbl + off0 + kk, &Bl[nxt][lb0]); GL16(Bbl + off1 + kk, &Bl[nxt][lb1]); }
    __builtin_amdgcn_sched_barrier(0);
    CLUSTER24(0, a0h, a0l, a1h, a1l)
    __builtin_amdgcn_s_barrier();

    // ---- W1: issue pair45; stage Ah; MFMA c23 (pair45 in flight)
    bf16x8 a4h = *(const bf16x8*)&Ah[cur][aof(4)];
    bf16x8 a4l = *(const bf16x8*)&Al[cur][aof(4)];
    bf16x8 a5h = *(const bf16x8*)&Ah[cur][aof(5)];
    bf16x8 a5l = *(const bf16x8*)&Al[cur][aof(5)];
    if (stg) { GL16(Abh + off0 + kk, &Ah[nxt][lb0]); GL16(Abh + off1 + kk, &Ah[nxt][lb1]); }
    __builtin_amdgcn_sched_barrier(0);
    CLUSTER24(2, a2h, a2l, a3h, a3l)
    __builtin_amdgcn_s_barrier();

    // ---- W2: issue pair67; stage Al; MFMA c45 (pair67 in flight)
    bf16x8 a6h = *(const bf16x8*)&Ah[cur][aof(6)];
    bf16x8 a6l = *(const bf16x8*)&Al[cur][aof(6)];
    bf16x8 a7h = *(const bf16x8*)&Ah[cur][aof(7)];
    bf16x8 a7l = *(const bf16x8*)&Al[cur][aof(7)];
    if (stg) { GL16(Abl + off0 + kk, &Al[nxt][lb0]); GL16(Abl + off1 + kk, &Al[nxt][lb1]); }
    __builtin_amdgcn_sched_barrier(0);
    CLUSTER24(4, a4h, a4l, a5h, a5l)
    __builtin_amdgcn_s_barrier();

    // ---- W3: MFMA c67; end barrier protects cur from next boundary's GL16 (WAR)
    __builtin_amdgcn_sched_barrier(0);
    CLUSTER24(6, a6h, a6l, a7h, a7l)
    __builtin_amdgcn_s_barrier();
  }

  // epilogue: bias+relu, bf16 h store, scores2 (each wave owns one full batch
  // row-range -> intra-wave shuffle reduce only, no LDS reduction needed)
  const int bb = b0 + wm;
  float bias[4];
#pragma unroll
  for (int j = 0; j < 4; ++j) bias[j] = b1[hc0 + wn * 64 + j * 16 + ml];
  float sc[4] = {0.f, 0.f, 0.f, 0.f};
#pragma unroll
  for (int i = 0; i < 8; ++i) {
#pragma unroll
    for (int r = 0; r < 4; ++r) {
      const int n = i * 16 + qd * 4 + r;
      const float wsn = ws2[n];
      unsigned short* hp = h + ((size_t)(bb * N_ + n)) * H_ + hc0 + wn * 64;
#pragma unroll
      for (int j = 0; j < 4; ++j) {
        float v = acc[i][j][r] + bias[j];
        v = fmaxf(v, 0.f);
        hp[j * 16 + ml] = f2bf(v);
        sc[j] += v * wsn;
      }
    }
  }
#pragma unroll
  for (int j = 0; j < 4; ++j) {
    sc[j] += __shfl_xor(sc[j], 16);
    sc[j] += __shfl_xor(sc[j], 32);
  }
  if (lane < 16) {
#pragma unroll
    for (int j = 0; j < 4; ++j)
      scores2[(size_t)bb * H_ + hc0 + wn * 64 + j * 16 + lane] = sc[j];
  }
}

// ---------------------------------------------------------------------------
// GEMM2: out = hcomp * W2^T + b2, single bf16 MFMA, fp32 out.
// NEW (round 4): ported to the gemm1 structure — 256(n: 2 batches)x256(d)
// tile, 8 waves (2x4), BK=32, double-buffered 64 KiB LDS, 4 read-ahead
// windows/K-tile (8 MFMA each), counted vmcnt(2) at boundaries, raw
// s_barrier, setprio. Per acc element still exactly one MFMA per K-tile in
// ascending kt order -> out is bitwise identical to the old gemm2.
// ---------------------------------------------------------------------------
#define MF2(d, a, b) d = __builtin_amdgcn_mfma_f32_16x16x32_bf16(a, b, d, 0, 0, 0)

#define CLUSTER8(i0, A0, A1) \
  __builtin_amdgcn_s_setprio(1); \
  { _Pragma("unroll") \
    for (int j = 0; j < 4; ++j) { \
      MF2(acc[i0][j], A0, bh[j]); \
      MF2(acc[(i0) + 1][j], A1, bh[j]); \
    } } \
  __builtin_amdgcn_s_setprio(0);

__global__ __launch_bounds__(512, 2) void gemm2_kernel(
    const unsigned short* __restrict__ hcomp, const unsigned short* __restrict__ w2b,
    const float* __restrict__ b2, float* __restrict__ out) {
  const int d0 = blockIdx.x * 256;
  const int b0 = blockIdx.y * 2;
  const int t = threadIdx.x, w = t >> 6, lane = t & 63;
  const int ml = lane & 15, qd = lane >> 4;
  const int wm = w >> 2, wn = w & 3;   // 2(m) x 4(n) wave grid

  __shared__ unsigned short A2[2][8192], B2[2][8192];   // 64 KiB

  floatx4 acc[8][4] = {};

  const unsigned short* Ab = hcomp + (size_t)b0 * N_ * K2P;  // 256 rows (2 batches)
  const unsigned short* Bb = w2b + (size_t)d0 * K2P;         // 256 d rows

  const int c0 = w * 64 + lane, c1 = c0 + 512;
  const size_t off0 = (size_t)(((c0 >> 6) << 4) | (c0 & 15)) * K2P + (size_t)(((c0 >> 4) & 3) * 8);
  const size_t off1 = (size_t)(((c1 >> 6) << 4) | (c1 & 15)) * K2P + (size_t)(((c1 >> 4) & 3) * 8);
  const int lb0 = (w * 64) * 8, lb1 = (512 + w * 64) * 8;

  auto aof = [&](int i) { return ((wm * 8 + i) * 64 + qd * 16 + ml) * 8; };

  // prologue: stage K-tile 0 (4 loads/wave)
  GL16(Ab + off0, &A2[0][lb0]); GL16(Ab + off1, &A2[0][lb1]);
  GL16(Bb + off0, &B2[0][lb0]); GL16(Bb + off1, &B2[0][lb1]);

  for (int kt = 0; kt < KT2; ++kt) {
    const int cur = kt & 1, nxt = cur ^ 1;
    const size_t kk = (size_t)(kt + 1) * 32;
    const bool stg = (kt + 1 < KT2);

    // ---- boundary: prefetch A pair into nxt, counted wait for cur
    if (stg) { GL16(Ab + off0 + kk, &A2[nxt][lb0]); GL16(Ab + off1 + kk, &A2[nxt][lb1]); }
    if (stg) asm volatile("s_waitcnt vmcnt(2)" ::: "memory");
    else     asm volatile("s_waitcnt vmcnt(0)" ::: "memory");
    __builtin_amdgcn_s_barrier();

    // ---- W0: read B frags + a0..a3; stage B pair; MFMA c01 (a2/a3 in flight)
    bf16x8 bh[4];
#pragma unroll
    for (int j = 0; j < 4; ++j) {
      const int bo = ((wn * 4 + j) * 64 + qd * 16 + ml) * 8;
      bh[j] = *(const bf16x8*)&B2[cur][bo];
    }
    bf16x8 a0 = *(const bf16x8*)&A2[cur][aof(0)];
    bf16x8 a1 = *(const bf16x8*)&A2[cur][aof(1)];
    bf16x8 a2 = *(const bf16x8*)&A2[cur][aof(2)];
    bf16x8 a3 = *(const bf16x8*)&A2[cur][aof(3)];
    if (stg) { GL16(Bb + off0 + kk, &B2[nxt][lb0]); GL16(Bb + off1 + kk, &B2[nxt][lb1]); }
    __builtin_amdgcn_sched_barrier(0);
    CLUSTER8(0, a0, a1)
    __builtin_amdgcn_s_barrier();

    // ---- W1: read a4/a5; MFMA c23
    bf16x8 a4 = *(const bf16x8*)&A2[cur][aof(4)];
    bf16x8 a5 = *(const bf16x8*)&A2[cur][aof(5)];
    __builtin_amdgcn_sched_barrier(0);
    CLUSTER8(2, a2, a3)
    __builtin_amdgcn_s_barrier();

    // ---- W2: read a6/a7; MFMA c45
    bf16x8 a6 = *(const bf16x8*)&A2[cur][aof(6)];
    bf16x8 a7 = *(const bf16x8*)&A2[cur][aof(7)];
    __builtin_amdgcn_sched_barrier(0);
    CLUSTER8(4, a4, a5)
    __builtin_amdgcn_s_barrier();

    // ---- W3: MFMA c67; end barrier protects cur from next boundary GL16 (WAR)
    __builtin_amdgcn_sched_barrier(0);
    CLUSTER8(6, a6, a7)
    __builtin_amdgcn_s_barrier();
  }

  // epilogue: bias + fp32 store; wave wm owns batch b0+wm, all 128 n-rows
  const int bb = b0 + wm;
  float bias[4];
#pragma unroll
  for (int j = 0; j < 4; ++j) bias[j] = b2[d0 + wn * 64 + j * 16 + ml];
#pragma unroll
  for (int i = 0; i < 8; ++i) {
#pragma unroll
    for (int r = 0; r < 4; ++r) {
      const int n = i * 16 + qd * 4 + r;
      float* op = out + ((size_t)(bb * N_ + n)) * D_ + d0 + wn * 64;
#pragma unroll
      for (int j = 0; j < 4; ++j)
        op[j * 16 + ml] = acc[i][j][r] + bias[j];
    }
  }
}

// ---------------------------------------------------------------------------
extern "C" void kernel_launch(void* const* d_in, const int* in_sizes, int n_in,
                              void* d_out, int out_size, void* d_ws, size_t ws_size,
                              hipStream_t stream) {
  (void)in_sizes; (void)n_in; (void)out_size; (void)ws_size;
  const float* x   = (const float*)d_in[0];
  const float* ws1 = (const float*)d_in[1];
  const float* W1  = (const float*)d_in[3];
  const float* b1  = (const float*)d_in[4];
  const float* ws2 = (const float*)d_in[5];
  const float* W2  = (const float*)d_in[7];
  const float* b2  = (const float*)d_in[8];
  float* out = (float*)d_out;

  char* p = (char*)d_ws;
  auto alloc = [&](size_t bytes) {
    char* r = p;
    p += (bytes + 255) & ~(size_t)255;
    return r;
  };
  float* scores1 = (float*)alloc((size_t)B_ * D_ * sizeof(float));
  int*   idx1    = (int*)  alloc((size_t)B_ * K1_ * sizeof(int));
  float* scores2 = (float*)alloc((size_t)B_ * H_ * sizeof(float));
  int*   idx2    = (int*)  alloc((size_t)B_ * K2_ * sizeof(int));
  unsigned short* w1h = (unsigned short*)alloc((size_t)H_ * K1P * sizeof(short));
  unsigned short* w1l = (unsigned short*)alloc((size_t)H_ * K1P * sizeof(short));
  unsigned short* w2b = (unsigned short*)alloc((size_t)D_ * K2P * sizeof(short));
  unsigned short* h   = (unsigned short*)alloc((size_t)B_ * N_ * H_ * sizeof(short));
  // region shared by {xch, xcl} (live through gemm1) and hcomp (live after)
  size_t xc_bytes    = (size_t)B_ * N_ * K1P * sizeof(short);   // 54.5 MB each
  size_t hcomp_bytes = (size_t)B_ * N_ * K2P * sizeof(short);   // 216 MB
  char* region = alloc(hcomp_bytes > 2 * xc_bytes ? hcomp_bytes : 2 * xc_bytes);
  unsigned short* xch   = (unsigned short*)region;
  unsigned short* xcl   = (unsigned short*)(region + xc_bytes);
  unsigned short* hcomp = (unsigned short*)region;  // aliases xc after gemm1 (stream-ordered)

  scores1_kernel<<<B_, 256, 0, stream>>>(x, ws1, scores1);
  topk_kernel<<<B_, 256, 0, stream>>>(scores1, D_, K1_, idx1);
  xprep_kernel<<<B_ * N_, 256, 0, stream>>>(x, idx1, xch, xcl);
  w1split_kernel<<<(H_ * K1P) / 256, 256, 0, stream>>>(W1, w1h, w1l);
  w2conv_kernel<<<(D_ * K2P) / 256, 256, 0, stream>>>(W2, w2b);
  gemm1_kernel<<<dim3(H_ / 256, B_ / 2), 512, 0, stream>>>(xch, xcl, w1h, w1l, b1, ws2, h, scores2);
  topk_kernel<<<B_, 256, 0, stream>>>(scores2, H_, K2_, idx2);
  hcompact_kernel<<<B_ * N_, 256, 0, stream>>>(h, idx2, hcomp);
  gemm2_kernel<<<dim3(D_ / 256, B_ / 2), 512, 0, stream>>>(hcomp, w2b, b2, out);
}

// Round 5
// 1436.720 us; speedup vs baseline: 1.3292x; 1.1485x over previous
//
#include <hip/hip_runtime.h>
#include <cstdint>
#include <cstddef>

#define B_  256
#define N_  128
#define D_  1024
#define H_  4096
#define K1_ 819
#define K2_ 3276
#define K1P 832      // 26 * 32
#define K2P 3328     // 52 * 64 (padded; pad region is zero on both operands)
#define KT1 (K1P / 32)
#define KT2D (K2P / 64)
#define LDI1 820     // idx1 row stride (ints), 16B-aligned
#define LDI2 3280    // idx2 row stride (ints), 16B-aligned

typedef __bf16 bf16x8 __attribute__((ext_vector_type(8)));
typedef float floatx4 __attribute__((ext_vector_type(4)));
typedef unsigned short ushort4v __attribute__((ext_vector_type(4)));

__device__ __forceinline__ unsigned short f2bf(float f) {
  unsigned u = __float_as_uint(f);
  u += 0x7FFFu + ((u >> 16) & 1u);   // RNE
  return (unsigned short)(u >> 16);
}
__device__ __forceinline__ float bf2f(unsigned short s) {
  return __uint_as_float(((unsigned)s) << 16);
}

// async global->LDS, 16B per lane; lds dest is wave-uniform base + lane*16
#define GL16(gp, lp) __builtin_amdgcn_global_load_lds( \
    (const __attribute__((address_space(1))) void*)(gp), \
    (__attribute__((address_space(3))) void*)(lp), 16, 0, 0)

// ---------------------------------------------------------------------------
// scores1[b,c] = sum_n x[b,n,c] * ws1[n], fp64 accumulate (selection-critical)
// ---------------------------------------------------------------------------
__global__ __launch_bounds__(256) void scores1_kernel(const float* __restrict__ x,
                                                      const float* __restrict__ ws1,
                                                      float* __restrict__ scores1) {
  int b = blockIdx.x, t = threadIdx.x;
  __shared__ float w[N_];
  if (t < N_) w[t] = ws1[t];
  __syncthreads();
  const float* xb = x + (size_t)b * N_ * D_;
  double a0 = 0, a1 = 0, a2 = 0, a3 = 0;
  for (int n = 0; n < N_; ++n) {
    double wv = (double)w[n];
    const float* r = xb + (size_t)n * D_ + t;
    a0 += (double)r[0]   * wv;
    a1 += (double)r[256] * wv;
    a2 += (double)r[512] * wv;
    a3 += (double)r[768] * wv;
  }
  float* s = scores1 + (size_t)b * D_ + t;
  s[0]   = (float)a0;
  s[256] = (float)a1;
  s[512] = (float)a2;
  s[768] = (float)a3;
}

// ---------------------------------------------------------------------------
// Exact top-K per row: 8-bit radix select + index-ordered compaction.
// Round 5: compaction scan is wave-level shfl_up + one LDS exchange
// (2 barriers/chunk vs 16); cross-chunk bases kept in registers.
// Identical integer math -> identical selection and ordering.
// ---------------------------------------------------------------------------
__global__ __launch_bounds__(256) void topk_kernel(const float* __restrict__ scores,
                                                   int C, int K, int ldi,
                                                   int* __restrict__ idx_out) {
  int b = blockIdx.x, t = threadIdx.x;
  const int lane = t & 63, wv = t >> 6;
  __shared__ unsigned keys[4096];
  __shared__ unsigned hist[256];
  __shared__ unsigned wsum[4];
  __shared__ unsigned s_sel, s_want;

  for (int c = t; c < C; c += 256) {
    unsigned u = __float_as_uint(scores[(size_t)b * C + c]);
    keys[c] = u ^ ((u & 0x80000000u) ? 0xFFFFFFFFu : 0x80000000u);
  }
  if (t == 0) s_want = (unsigned)K;
  __syncthreads();

  unsigned prefix = 0;
  for (int shift = 24; shift >= 0; shift -= 8) {
    hist[t] = 0u;
    __syncthreads();
    unsigned mask = (shift == 24) ? 0u : (0xFFFFFFFFu << (shift + 8));
    for (int c = t; c < C; c += 256) {
      unsigned k = keys[c];
      if ((k & mask) == (prefix & mask))
        atomicAdd(&hist[(k >> shift) & 0xFFu], 1u);
    }
    __syncthreads();
    if (t == 0) {
      unsigned want = s_want, cum = 0u, sel = 0u;
      for (int d = 255; d >= 0; --d) {
        cum += hist[d];
        if (cum >= want) { sel = (unsigned)d; s_want = want - (cum - hist[d]); break; }
      }
      s_sel = sel;
    }
    __syncthreads();
    prefix |= (s_sel << shift);
  }
  unsigned kth = prefix;
  unsigned n_eq_keep = s_want;
  __syncthreads();

  unsigned base_gt = 0u, base_eq = 0u;
  int nch = C >> 8;
  for (int ch = 0; ch < nch; ++ch) {
    int c = (ch << 8) + t;
    unsigned k = keys[c];
    unsigned gt = (k > kth) ? 1u : 0u;
    unsigned eq = (k == kth) ? 1u : 0u;
    unsigned val = gt | (eq << 16);
    // wave-level inclusive scan (packed u16 fields; per-chunk counts <= 256)
    unsigned incl = val;
#pragma unroll
    for (int off = 1; off < 64; off <<= 1) {
      unsigned o = __shfl_up(incl, off, 64);
      if (lane >= off) incl += o;
    }
    if (lane == 63) wsum[wv] = incl;
    __syncthreads();
    unsigned pre = 0u, tot = 0u;
#pragma unroll
    for (int u = 0; u < 4; ++u) {
      unsigned s = wsum[u];
      tot += s;
      if (u < wv) pre += s;
    }
    unsigned excl = incl + pre - val;
    unsigned gt_ex = excl & 0xFFFFu, eq_ex = excl >> 16;
    unsigned eq_before = base_eq + eq_ex;
    bool keep = (gt != 0u) || ((eq != 0u) && (eq_before < n_eq_keep));
    unsigned kept_eq_before = (eq_before < n_eq_keep) ? eq_before : n_eq_keep;
    unsigned pos = base_gt + gt_ex + kept_eq_before;
    if (keep) idx_out[(size_t)b * ldi + pos] = c;
    base_gt += tot & 0xFFFFu;
    base_eq += tot >> 16;
    __syncthreads();   // wsum reuse guard for next chunk
  }
}

// ---------------------------------------------------------------------------
// Prep: gather + hi/lo bf16 split of x into xch/xcl [B][N][K1P]
// Round 5: 4 elems/thread, int4 idx loads, ushort4 stores.
// ---------------------------------------------------------------------------
__global__ __launch_bounds__(256) void xprep_kernel(const float* __restrict__ x,
                                                    const int* __restrict__ idx1,
                                                    unsigned short* __restrict__ xch,
                                                    unsigned short* __restrict__ xcl) {
  int bn = blockIdx.x;
  int b = bn >> 7;
  const int* idxb = idx1 + (size_t)b * LDI1;
  const float* xr = x + (size_t)bn * D_;
  unsigned short* oh = xch + (size_t)bn * K1P;
  unsigned short* ol = xcl + (size_t)bn * K1P;
  for (int j0 = threadIdx.x * 4; j0 < K1P; j0 += 1024) {
    ushort4v vh, vl;
    if (j0 + 3 < K1_) {
      int4 id = *(const int4*)&idxb[j0];
      float f0 = xr[id.x], f1 = xr[id.y], f2 = xr[id.z], f3 = xr[id.w];
      vh[0] = f2bf(f0); vl[0] = f2bf(f0 - bf2f(vh[0]));
      vh[1] = f2bf(f1); vl[1] = f2bf(f1 - bf2f(vh[1]));
      vh[2] = f2bf(f2); vl[2] = f2bf(f2 - bf2f(vh[2]));
      vh[3] = f2bf(f3); vl[3] = f2bf(f3 - bf2f(vh[3]));
    } else {
#pragma unroll
      for (int e = 0; e < 4; ++e) {
        int j = j0 + e;
        float v = (j < K1_) ? xr[idxb[j]] : 0.f;
        unsigned short hi = f2bf(v);
        vh[e] = hi;
        vl[e] = f2bf(v - bf2f(hi));
      }
    }
    *(ushort4v*)&oh[j0] = vh;
    *(ushort4v*)&ol[j0] = vl;
  }
}

// hi/lo split of W1 [H][K1] -> [H][K1P]
__global__ __launch_bounds__(256) void w1split_kernel(const float* __restrict__ W1,
                                                      unsigned short* __restrict__ w1h,
                                                      unsigned short* __restrict__ w1l) {
  int e = blockIdx.x * 256 + threadIdx.x;
  int k = e % K1P, row = e / K1P;
  float v = (k < K1_) ? W1[(size_t)row * K1_ + k] : 0.f;
  unsigned short hi = f2bf(v);
  unsigned short lo = f2bf(v - bf2f(hi));
  w1h[e] = hi;
  w1l[e] = lo;
}

// bf16 convert of W2 [D][K2] -> [D][K2P] (pad zeros)
__global__ __launch_bounds__(256) void w2conv_kernel(const float* __restrict__ W2,
                                                     unsigned short* __restrict__ w2b) {
  int e = blockIdx.x * 256 + threadIdx.x;
  int k = e % K2P, row = e / K2P;
  w2b[e] = (k < K2_) ? f2bf(W2[(size_t)row * K2_ + k]) : (unsigned short)0;
}

// gather h [B][N][H] bf16 -> hcomp [B][N][K2P] bf16
// Round 5: 4 elems/thread, int4 idx loads, ushort4 stores.
__global__ __launch_bounds__(256) void hcompact_kernel(const unsigned short* __restrict__ h,
                                                       const int* __restrict__ idx2,
                                                       unsigned short* __restrict__ hcomp) {
  int bn = blockIdx.x;
  int b = bn >> 7;
  const int* idxb = idx2 + (size_t)b * LDI2;
  const unsigned short* hr = h + (size_t)bn * H_;
  unsigned short* o = hcomp + (size_t)bn * K2P;
  for (int j0 = threadIdx.x * 4; j0 < K2P; j0 += 1024) {
    ushort4v v;
    if (j0 < K2_) {                       // K2_ % 4 == 0: chunk fully valid
      int4 id = *(const int4*)&idxb[j0];
      v[0] = hr[id.x]; v[1] = hr[id.y]; v[2] = hr[id.z]; v[3] = hr[id.w];
    } else {
      v[0] = 0; v[1] = 0; v[2] = 0; v[3] = 0;
    }
    *(ushort4v*)&o[j0] = v;
  }
}

// ---------------------------------------------------------------------------
// GEMM1: h = relu(xc * W1^T + b1) via bf16x3 split MFMA; bf16 h store + fused
// scores2 epilogue. (Unchanged from round 3 — 722 us, MfmaUtil 41%.)
// ---------------------------------------------------------------------------
#define MF1(d, a, b) d = __builtin_amdgcn_mfma_f32_16x16x32_bf16(a, b, d, 0, 0, 0)

#define CLUSTER24(i0, A0H, A0L, A1H, A1L) \
  __builtin_amdgcn_s_setprio(1); \
  { _Pragma("unroll") \
    for (int j = 0; j < 4; ++j) { \
      MF1(acc[i0][j], A0H, bh[j]); \
      MF1(acc[i0][j], A0H, bl[j]); \
      MF1(acc[i0][j], A0L, bh[j]); \
      MF1(acc[(i0) + 1][j], A1H, bh[j]); \
      MF1(acc[(i0) + 1][j], A1H, bl[j]); \
      MF1(acc[(i0) + 1][j], A1L, bh[j]); \
    } } \
  __builtin_amdgcn_s_setprio(0);

__global__ __launch_bounds__(512, 2) void gemm1_kernel(
    const unsigned short* __restrict__ xch, const unsigned short* __restrict__ xcl,
    const unsigned short* __restrict__ w1h, const unsigned short* __restrict__ w1l,
    const float* __restrict__ b1, const float* __restrict__ ws2,
    unsigned short* __restrict__ h, float* __restrict__ scores2) {
  const int hc0 = blockIdx.x * 256;
  const int b0 = blockIdx.y * 2;
  const int t = threadIdx.x, w = t >> 6, lane = t & 63;
  const int ml = lane & 15, qd = lane >> 4;
  const int wm = w >> 2, wn = w & 3;   // 2(m) x 4(n) wave grid

  __shared__ unsigned short Ah[2][8192], Al[2][8192], Bh[2][8192], Bl[2][8192];

  floatx4 acc[8][4] = {};

  const unsigned short* Abh = xch + (size_t)b0 * N_ * K1P;
  const unsigned short* Abl = xcl + (size_t)b0 * N_ * K1P;
  const unsigned short* Bbh = w1h + (size_t)hc0 * K1P;
  const unsigned short* Bbl = w1l + (size_t)hc0 * K1P;

  const int c0 = w * 64 + lane, c1 = c0 + 512;
  const size_t off0 = (size_t)(((c0 >> 6) << 4) | (c0 & 15)) * K1P + (size_t)(((c0 >> 4) & 3) * 8);
  const size_t off1 = (size_t)(((c1 >> 6) << 4) | (c1 & 15)) * K1P + (size_t)(((c1 >> 4) & 3) * 8);
  const int lb0 = (w * 64) * 8;
  const int lb1 = (512 + w * 64) * 8;

  auto aof = [&](int i) { return ((wm * 8 + i) * 64 + qd * 16 + ml) * 8; };

  GL16(Abh + off0, &Ah[0][lb0]); GL16(Abh + off1, &Ah[0][lb1]);
  GL16(Abl + off0, &Al[0][lb0]); GL16(Abl + off1, &Al[0][lb1]);
  GL16(Bbh + off0, &Bh[0][lb0]); GL16(Bbh + off1, &Bh[0][lb1]);
  GL16(Bbl + off0, &Bl[0][lb0]); GL16(Bbl + off1, &Bl[0][lb1]);

  for (int kt = 0; kt < KT1; ++kt) {
    const int cur = kt & 1, nxt = cur ^ 1;
    const size_t kk = (size_t)(kt + 1) * 32;
    const bool stg = (kt + 1 < KT1);

    if (stg) { GL16(Bbh + off0 + kk, &Bh[nxt][lb0]); GL16(Bbh + off1 + kk, &Bh[nxt][lb1]); }
    if (stg) asm volatile("s_waitcnt vmcnt(2)" ::: "memory");
    else     asm volatile("s_waitcnt vmcnt(0)" ::: "memory");
    __builtin_amdgcn_s_barrier();

    bf16x8 bh[4], bl[4];
#pragma unroll
    for (int j = 0; j < 4; ++j) {
      const int bo = ((wn * 4 + j) * 64 + qd * 16 + ml) * 8;
      bh[j] = *(const bf16x8*)&Bh[cur][bo];
      bl[j] = *(const bf16x8*)&Bl[cur][bo];
    }
    bf16x8 a0h = *(const bf16x8*)&Ah[cur][aof(0)];
    bf16x8 a0l = *(const bf16x8*)&Al[cur][aof(0)];
    bf16x8 a1h = *(const bf16x8*)&Ah[cur][aof(1)];
    bf16x8 a1l = *(const bf16x8*)&Al[cur][aof(1)];
    bf16x8 a2h = *(const bf16x8*)&Ah[cur][aof(2)];
    bf16x8 a2l = *(const bf16x8*)&Al[cur][aof(2)];
    bf16x8 a3h = *(const bf16x8*)&Ah[cur][aof(3)];
    bf16x8 a3l = *(const bf16x8*)&Al[cur][aof(3)];
    if (stg) { GL16(Bbl + off0 + kk, &Bl[nxt][lb0]); GL16(Bbl + off1 + kk, &Bl[nxt][lb1]); }
    __builtin_amdgcn_sched_barrier(0);
    CLUSTER24(0, a0h, a0l, a1h, a1l)
    __builtin_amdgcn_s_barrier();

    bf16x8 a4h = *(const bf16x8*)&Ah[cur][aof(4)];
    bf16x8 a4l = *(const bf16x8*)&Al[cur][aof(4)];
    bf16x8 a5h = *(const bf16x8*)&Ah[cur][aof(5)];
    bf16x8 a5l = *(const bf16x8*)&Al[cur][aof(5)];
    if (stg) { GL16(Abh + off0 + kk, &Ah[nxt][lb0]); GL16(Abh + off1 + kk, &Ah[nxt][lb1]); }
    __builtin_amdgcn_sched_barrier(0);
    CLUSTER24(2, a2h, a2l, a3h, a3l)
    __builtin_amdgcn_s_barrier();

    bf16x8 a6h = *(const bf16x8*)&Ah[cur][aof(6)];
    bf16x8 a6l = *(const bf16x8*)&Al[cur][aof(6)];
    bf16x8 a7h = *(const bf16x8*)&Ah[cur][aof(7)];
    bf16x8 a7l = *(const bf16x8*)&Al[cur][aof(7)];
    if (stg) { GL16(Abl + off0 + kk, &Al[nxt][lb0]); GL16(Abl + off1 + kk, &Al[nxt][lb1]); }
    __builtin_amdgcn_sched_barrier(0);
    CLUSTER24(4, a4h, a4l, a5h, a5l)
    __builtin_amdgcn_s_barrier();

    __builtin_amdgcn_sched_barrier(0);
    CLUSTER24(6, a6h, a6l, a7h, a7l)
    __builtin_amdgcn_s_barrier();
  }

  const int bb = b0 + wm;
  float bias[4];
#pragma unroll
  for (int j = 0; j < 4; ++j) bias[j] = b1[hc0 + wn * 64 + j * 16 + ml];
  float sc[4] = {0.f, 0.f, 0.f, 0.f};
#pragma unroll
  for (int i = 0; i < 8; ++i) {
#pragma unroll
    for (int r = 0; r < 4; ++r) {
      const int n = i * 16 + qd * 4 + r;
      const float wsn = ws2[n];
      unsigned short* hp = h + ((size_t)(bb * N_ + n)) * H_ + hc0 + wn * 64;
#pragma unroll
      for (int j = 0; j < 4; ++j) {
        float v = acc[i][j][r] + bias[j];
        v = fmaxf(v, 0.f);
        hp[j * 16 + ml] = f2bf(v);
        sc[j] += v * wsn;
      }
    }
  }
#pragma unroll
  for (int j = 0; j < 4; ++j) {
    sc[j] += __shfl_xor(sc[j], 16);
    sc[j] += __shfl_xor(sc[j], 32);
  }
  if (lane < 16) {
#pragma unroll
    for (int j = 0; j < 4; ++j)
      scores2[(size_t)bb * H_ + hc0 + wn * 64 + j * 16 + lane] = sc[j];
  }
}

// ---------------------------------------------------------------------------
// GEMM2: out = hcomp * W2^T + b2.
// Round 5: BK=64 (two 32-halves per iter; K2P padded to 3328 = 52*64).
// 256x256 tile, 8 waves, double-buffered 128 KiB LDS, 4 windows of 16 MFMA,
// counted vmcnt(2) at boundaries only (52 vs 103 boundaries).
// Per acc element: one MFMA per 32-slab in ascending order; pad slab is
// all-zero on both operands (adds exact +0.0) -> out bitwise identical.
// ---------------------------------------------------------------------------
#define MF2(d, a, b) d = __builtin_amdgcn_mfma_f32_16x16x32_bf16(a, b, d, 0, 0, 0)

#define CL16(i0, A0, A1, A2r, A3, BB) \
  __builtin_amdgcn_s_setprio(1); \
  { _Pragma("unroll") \
    for (int j = 0; j < 4; ++j) { \
      MF2(acc[(i0)][j], A0, BB[j]); \
      MF2(acc[(i0) + 1][j], A1, BB[j]); \
      MF2(acc[(i0) + 2][j], A2r, BB[j]); \
      MF2(acc[(i0) + 3][j], A3, BB[j]); \
    } } \
  __builtin_amdgcn_s_setprio(0);

__global__ __launch_bounds__(512, 2) void gemm2_kernel(
    const unsigned short* __restrict__ hcomp, const unsigned short* __restrict__ w2b,
    const float* __restrict__ b2, float* __restrict__ out) {
  const int d0 = blockIdx.x * 256;
  const int b0 = blockIdx.y * 2;
  const int t = threadIdx.x, w = t >> 6, lane = t & 63;
  const int ml = lane & 15, qd = lane >> 4;
  const int wm = w >> 2, wn = w & 3;   // 2(m) x 4(n) wave grid

  __shared__ unsigned short As[2][2][8192], Bs[2][2][8192];   // 128 KiB

  floatx4 acc[8][4] = {};

  const unsigned short* Ab = hcomp + (size_t)b0 * N_ * K2P;   // 256 rows (2 batches)
  const unsigned short* Bb = w2b + (size_t)d0 * K2P;          // 256 d rows

  const int c0 = w * 64 + lane, c1 = c0 + 512;
  const size_t off0 = (size_t)(((c0 >> 6) << 4) | (c0 & 15)) * K2P + (size_t)(((c0 >> 4) & 3) * 8);
  const size_t off1 = (size_t)(((c1 >> 6) << 4) | (c1 & 15)) * K2P + (size_t)(((c1 >> 4) & 3) * 8);
  const int lb0 = (w * 64) * 8, lb1 = (512 + w * 64) * 8;

  auto aof = [&](int i) { return ((wm * 8 + i) * 64 + qd * 16 + ml) * 8; };
  auto bof = [&](int j) { return ((wn * 4 + j) * 64 + qd * 16 + ml) * 8; };

  // prologue: stage iter 0 fully (A h0/h1, B h0/h1 = 8 loads/wave)
  GL16(Ab + off0,      &As[0][0][lb0]); GL16(Ab + off1,      &As[0][0][lb1]);
  GL16(Ab + off0 + 32, &As[0][1][lb0]); GL16(Ab + off1 + 32, &As[0][1][lb1]);
  GL16(Bb + off0,      &Bs[0][0][lb0]); GL16(Bb + off1,      &Bs[0][0][lb1]);
  GL16(Bb + off0 + 32, &Bs[0][1][lb0]); GL16(Bb + off1 + 32, &Bs[0][1][lb1]);

  for (int kt = 0; kt < KT2D; ++kt) {
    const int cur = kt & 1, nxt = cur ^ 1;
    const size_t kk = (size_t)(kt + 1) * 64;
    const bool stg = (kt + 1 < KT2D);

    // boundary: prefetch A-h0(next); counted wait; barrier
    if (stg) { GL16(Ab + off0 + kk, &As[nxt][0][lb0]); GL16(Ab + off1 + kk, &As[nxt][0][lb1]); }
    if (stg) asm volatile("s_waitcnt vmcnt(2)" ::: "memory");
    else     asm volatile("s_waitcnt vmcnt(0)" ::: "memory");
    __builtin_amdgcn_s_barrier();

    // W0: read b(h0), a0-7(h0); stage A-h1(next); MFMA rows0-3 @ h0
    bf16x8 bh0[4];
#pragma unroll
    for (int j = 0; j < 4; ++j) bh0[j] = *(const bf16x8*)&Bs[cur][0][bof(j)];
    bf16x8 a0 = *(const bf16x8*)&As[cur][0][aof(0)];
    bf16x8 a1 = *(const bf16x8*)&As[cur][0][aof(1)];
    bf16x8 a2 = *(const bf16x8*)&As[cur][0][aof(2)];
    bf16x8 a3 = *(const bf16x8*)&As[cur][0][aof(3)];
    bf16x8 a4 = *(const bf16x8*)&As[cur][0][aof(4)];
    bf16x8 a5 = *(const bf16x8*)&As[cur][0][aof(5)];
    bf16x8 a6 = *(const bf16x8*)&As[cur][0][aof(6)];
    bf16x8 a7 = *(const bf16x8*)&As[cur][0][aof(7)];
    if (stg) { GL16(Ab + off0 + kk + 32, &As[nxt][1][lb0]); GL16(Ab + off1 + kk + 32, &As[nxt][1][lb1]); }
    __builtin_amdgcn_sched_barrier(0);
    CL16(0, a0, a1, a2, a3, bh0)
    __builtin_amdgcn_s_barrier();

    // W1: read b(h1), e0-3(h1); stage B-h0(next); MFMA rows4-7 @ h0
    bf16x8 bh1[4];
#pragma unroll
    for (int j = 0; j < 4; ++j) bh1[j] = *(const bf16x8*)&Bs[cur][1][bof(j)];
    bf16x8 e0 = *(const bf16x8*)&As[cur][1][aof(0)];
    bf16x8 e1 = *(const bf16x8*)&As[cur][1][aof(1)];
    bf16x8 e2 = *(const bf16x8*)&As[cur][1][aof(2)];
    bf16x8 e3 = *(const bf16x8*)&As[cur][1][aof(3)];
    if (stg) { GL16(Bb + off0 + kk, &Bs[nxt][0][lb0]); GL16(Bb + off1 + kk, &Bs[nxt][0][lb1]); }
    __builtin_amdgcn_sched_barrier(0);
    CL16(4, a4, a5, a6, a7, bh0)
    __builtin_amdgcn_s_barrier();

    // W2: read e4-7(h1); stage B-h1(next); MFMA rows0-3 @ h1
    bf16x8 e4 = *(const bf16x8*)&As[cur][1][aof(4)];
    bf16x8 e5 = *(const bf16x8*)&As[cur][1][aof(5)];
    bf16x8 e6 = *(const bf16x8*)&As[cur][1][aof(6)];
    bf16x8 e7 = *(const bf16x8*)&As[cur][1][aof(7)];
    if (stg) { GL16(Bb + off0 + kk + 32, &Bs[nxt][1][lb0]); GL16(Bb + off1 + kk + 32, &Bs[nxt][1][lb1]); }
    __builtin_amdgcn_sched_barrier(0);
    CL16(0, e0, e1, e2, e3, bh1)
    __builtin_amdgcn_s_barrier();

    // W3: MFMA rows4-7 @ h1
    __builtin_amdgcn_sched_barrier(0);
    CL16(4, e4, e5, e6, e7, bh1)
    __builtin_amdgcn_s_barrier();
  }

  // epilogue: bias + fp32 store; wave wm owns batch b0+wm, all 128 n-rows
  const int bb = b0 + wm;
  float bias[4];
#pragma unroll
  for (int j = 0; j < 4; ++j) bias[j] = b2[d0 + wn * 64 + j * 16 + ml];
#pragma unroll
  for (int i = 0; i < 8; ++i) {
#pragma unroll
    for (int r = 0; r < 4; ++r) {
      const int n = i * 16 + qd * 4 + r;
      float* op = out + ((size_t)(bb * N_ + n)) * D_ + d0 + wn * 64;
#pragma unroll
      for (int j = 0; j < 4; ++j)
        op[j * 16 + ml] = acc[i][j][r] + bias[j];
    }
  }
}

// ---------------------------------------------------------------------------
extern "C" void kernel_launch(void* const* d_in, const int* in_sizes, int n_in,
                              void* d_out, int out_size, void* d_ws, size_t ws_size,
                              hipStream_t stream) {
  (void)in_sizes; (void)n_in; (void)out_size; (void)ws_size;
  const float* x   = (const float*)d_in[0];
  const float* ws1 = (const float*)d_in[1];
  const float* W1  = (const float*)d_in[3];
  const float* b1  = (const float*)d_in[4];
  const float* ws2 = (const float*)d_in[5];
  const float* W2  = (const float*)d_in[7];
  const float* b2  = (const float*)d_in[8];
  float* out = (float*)d_out;

  char* p = (char*)d_ws;
  auto alloc = [&](size_t bytes) {
    char* r = p;
    p += (bytes + 255) & ~(size_t)255;
    return r;
  };
  float* scores1 = (float*)alloc((size_t)B_ * D_ * sizeof(float));
  int*   idx1    = (int*)  alloc((size_t)B_ * LDI1 * sizeof(int));
  float* scores2 = (float*)alloc((size_t)B_ * H_ * sizeof(float));
  int*   idx2    = (int*)  alloc((size_t)B_ * LDI2 * sizeof(int));
  unsigned short* w1h = (unsigned short*)alloc((size_t)H_ * K1P * sizeof(short));
  unsigned short* w1l = (unsigned short*)alloc((size_t)H_ * K1P * sizeof(short));
  unsigned short* w2b = (unsigned short*)alloc((size_t)D_ * K2P * sizeof(short));
  unsigned short* h   = (unsigned short*)alloc((size_t)B_ * N_ * H_ * sizeof(short));
  // region shared by {xch, xcl} (live through gemm1) and hcomp (live after)
  size_t xc_bytes    = (size_t)B_ * N_ * K1P * sizeof(short);   // 54.5 MB each
  size_t hcomp_bytes = (size_t)B_ * N_ * K2P * sizeof(short);   // 218 MB
  char* region = alloc(hcomp_bytes > 2 * xc_bytes ? hcomp_bytes : 2 * xc_bytes);
  unsigned short* xch   = (unsigned short*)region;
  unsigned short* xcl   = (unsigned short*)(region + xc_bytes);
  unsigned short* hcomp = (unsigned short*)region;  // aliases xc after gemm1 (stream-ordered)

  scores1_kernel<<<B_, 256, 0, stream>>>(x, ws1, scores1);
  topk_kernel<<<B_, 256, 0, stream>>>(scores1, D_, K1_, LDI1, idx1);
  xprep_kernel<<<B_ * N_, 256, 0, stream>>>(x, idx1, xch, xcl);
  w1split_kernel<<<(H_ * K1P) / 256, 256, 0, stream>>>(W1, w1h, w1l);
  w2conv_kernel<<<(D_ * K2P) / 256, 256, 0, stream>>>(W2, w2b);
  gemm1_kernel<<<dim3(H_ / 256, B_ / 2), 512, 0, stream>>>(xch, xcl, w1h, w1l, b1, ws2, h, scores2);
  topk_kernel<<<B_, 256, 0, stream>>>(scores2, H_, K2_, LDI2, idx2);
  hcompact_kernel<<<B_ * N_, 256, 0, stream>>>(h, idx2, hcomp);
  gemm2_kernel<<<dim3(D_ / 256, B_ / 2), 512, 0, stream>>>(hcomp, w2b, b2, out);
}

// Round 7
// 1362.469 us; speedup vs baseline: 1.4016x; 1.0545x over previous
//
#include <hip/hip_runtime.h>
#include <cstdint>
#include <cstddef>

#define B_  256
#define N_  128
#define D_  1024
#define H_  4096
#define K1_ 819
#define K2_ 3276
#define K1P 832      // 26 * 32
#define K2P 3328     // 52 * 64 (padded; pad region is zero on both operands)
#define KT1 (K1P / 32)
#define KT2D (K2P / 64)
#define LDI1 820     // idx1 row stride (ints), 16B-aligned
#define LDI2 3280    // idx2 row stride (ints), 16B-aligned

typedef __bf16 bf16x8 __attribute__((ext_vector_type(8)));
typedef float floatx4 __attribute__((ext_vector_type(4)));
typedef unsigned short ushort4v __attribute__((ext_vector_type(4)));

__device__ __forceinline__ unsigned short f2bf(float f) {
  unsigned u = __float_as_uint(f);
  u += 0x7FFFu + ((u >> 16) & 1u);   // RNE
  return (unsigned short)(u >> 16);
}
__device__ __forceinline__ float bf2f(unsigned short s) {
  return __uint_as_float(((unsigned)s) << 16);
}

// async global->LDS, 16B per lane; lds dest is wave-uniform base + lane*16
#define GL16(gp, lp) __builtin_amdgcn_global_load_lds( \
    (const __attribute__((address_space(1))) void*)(gp), \
    (__attribute__((address_space(3))) void*)(lp), 16, 0, 0)

// ---------------------------------------------------------------------------
// scores1[b,c] = sum_n x[b,n,c] * ws1[n], fp64 accumulate (selection-critical)
// 1024 threads/block, one channel per thread (16 waves/CU vs 4).
// Per-channel accumulation chain is n-ascending exactly as before -> bitwise
// identical scores.
// ---------------------------------------------------------------------------
__global__ __launch_bounds__(1024) void scores1_kernel(const float* __restrict__ x,
                                                       const float* __restrict__ ws1,
                                                       float* __restrict__ scores1) {
  int b = blockIdx.x, t = threadIdx.x;
  __shared__ float w[N_];
  if (t < N_) w[t] = ws1[t];
  __syncthreads();
  const float* xb = x + (size_t)b * N_ * D_ + t;
  double a = 0;
  for (int n = 0; n < N_; ++n)
    a += (double)xb[(size_t)n * D_] * (double)w[n];
  scores1[(size_t)b * D_ + t] = (float)a;
}

// ---------------------------------------------------------------------------
// Exact top-K per row: 8-bit radix select + index-ordered compaction.
// Bin selection parallelized via 256-thread suffix-sum scan (replaces the
// t==0 serial 256-iteration sweep). Identical integer math:
// suf[d] = sum_{j>=d} hist[j]; selected d is the unique bin with
// suf[d] >= want && suf[d+1] < want  (== first d descending with cum>=want).
// ---------------------------------------------------------------------------
__global__ __launch_bounds__(256) void topk_kernel(const float* __restrict__ scores,
                                                   int C, int K, int ldi,
                                                   int* __restrict__ idx_out) {
  int b = blockIdx.x, t = threadIdx.x;
  const int lane = t & 63, wv = t >> 6;
  __shared__ unsigned keys[4096];
  __shared__ unsigned hist[256];
  __shared__ unsigned wsum[4];
  __shared__ unsigned s_sel, s_want;

  for (int c = t; c < C; c += 256) {
    unsigned u = __float_as_uint(scores[(size_t)b * C + c]);
    keys[c] = u ^ ((u & 0x80000000u) ? 0xFFFFFFFFu : 0x80000000u);
  }
  if (t == 0) s_want = (unsigned)K;
  __syncthreads();

  unsigned prefix = 0;
  for (int shift = 24; shift >= 0; shift -= 8) {
    hist[t] = 0u;
    __syncthreads();
    unsigned mask = (shift == 24) ? 0u : (0xFFFFFFFFu << (shift + 8));
    for (int c = t; c < C; c += 256) {
      unsigned k = keys[c];
      if ((k & mask) == (prefix & mask))
        atomicAdd(&hist[(k >> shift) & 0xFFu], 1u);
    }
    __syncthreads();
    const unsigned want = s_want;
    // suffix-sum scan: thread t computes suf[d] for d = 255 - t
    const unsigned hv = hist[255 - t];
    unsigned incl = hv;
#pragma unroll
    for (int off = 1; off < 64; off <<= 1) {
      unsigned o = __shfl_up(incl, off, 64);
      if (lane >= off) incl += o;
    }
    if (lane == 63) wsum[wv] = incl;
    __syncthreads();
    unsigned pre = 0u;
#pragma unroll
    for (int u = 0; u < 4; ++u)
      if (u < wv) pre += wsum[u];
    const unsigned suf = incl + pre;          // = sum_{j >= 255-t} hist[j]
    if (suf >= want && (suf - hv) < want) {   // exactly one thread
      s_sel = (unsigned)(255 - t);
      s_want = want - (suf - hv);
    }
    __syncthreads();
    prefix |= (s_sel << shift);
  }
  unsigned kth = prefix;
  unsigned n_eq_keep = s_want;
  __syncthreads();

  unsigned base_gt = 0u, base_eq = 0u;
  int nch = C >> 8;
  for (int ch = 0; ch < nch; ++ch) {
    int c = (ch << 8) + t;
    unsigned k = keys[c];
    unsigned gt = (k > kth) ? 1u : 0u;
    unsigned eq = (k == kth) ? 1u : 0u;
    unsigned val = gt | (eq << 16);
    // wave-level inclusive scan (packed u16 fields; per-chunk counts <= 256)
    unsigned incl = val;
#pragma unroll
    for (int off = 1; off < 64; off <<= 1) {
      unsigned o = __shfl_up(incl, off, 64);
      if (lane >= off) incl += o;
    }
    if (lane == 63) wsum[wv] = incl;
    __syncthreads();
    unsigned pre = 0u, tot = 0u;
#pragma unroll
    for (int u = 0; u < 4; ++u) {
      unsigned s = wsum[u];
      tot += s;
      if (u < wv) pre += s;
    }
    unsigned excl = incl + pre - val;
    unsigned gt_ex = excl & 0xFFFFu, eq_ex = excl >> 16;
    unsigned eq_before = base_eq + eq_ex;
    bool keep = (gt != 0u) || ((eq != 0u) && (eq_before < n_eq_keep));
    unsigned kept_eq_before = (eq_before < n_eq_keep) ? eq_before : n_eq_keep;
    unsigned pos = base_gt + gt_ex + kept_eq_before;
    if (keep) idx_out[(size_t)b * ldi + pos] = c;
    base_gt += tot & 0xFFFFu;
    base_eq += tot >> 16;
    __syncthreads();   // wsum reuse guard for next chunk
  }
}

// ---------------------------------------------------------------------------
// Prep: gather + hi/lo bf16 split of x into xch/xcl [B][N][K1P]
// 4 elems/thread, int4 idx loads, ushort4 stores.
// ---------------------------------------------------------------------------
__global__ __launch_bounds__(256) void xprep_kernel(const float* __restrict__ x,
                                                    const int* __restrict__ idx1,
                                                    unsigned short* __restrict__ xch,
                                                    unsigned short* __restrict__ xcl) {
  int bn = blockIdx.x;
  int b = bn >> 7;
  const int* idxb = idx1 + (size_t)b * LDI1;
  const float* xr = x + (size_t)bn * D_;
  unsigned short* oh = xch + (size_t)bn * K1P;
  unsigned short* ol = xcl + (size_t)bn * K1P;
  for (int j0 = threadIdx.x * 4; j0 < K1P; j0 += 1024) {
    ushort4v vh, vl;
    if (j0 + 3 < K1_) {
      int4 id = *(const int4*)&idxb[j0];
      float f0 = xr[id.x], f1 = xr[id.y], f2 = xr[id.z], f3 = xr[id.w];
      vh[0] = f2bf(f0); vl[0] = f2bf(f0 - bf2f(vh[0]));
      vh[1] = f2bf(f1); vl[1] = f2bf(f1 - bf2f(vh[1]));
      vh[2] = f2bf(f2); vl[2] = f2bf(f2 - bf2f(vh[2]));
      vh[3] = f2bf(f3); vl[3] = f2bf(f3 - bf2f(vh[3]));
    } else {
#pragma unroll
      for (int e = 0; e < 4; ++e) {
        int j = j0 + e;
        float v = (j < K1_) ? xr[idxb[j]] : 0.f;
        unsigned short hi = f2bf(v);
        vh[e] = hi;
        vl[e] = f2bf(v - bf2f(hi));
      }
    }
    *(ushort4v*)&oh[j0] = vh;
    *(ushort4v*)&ol[j0] = vl;
  }
}

// hi/lo split of W1 [H][K1] -> [H][K1P]
__global__ __launch_bounds__(256) void w1split_kernel(const float* __restrict__ W1,
                                                      unsigned short* __restrict__ w1h,
                                                      unsigned short* __restrict__ w1l) {
  int e = blockIdx.x * 256 + threadIdx.x;
  int k = e % K1P, row = e / K1P;
  float v = (k < K1_) ? W1[(size_t)row * K1_ + k] : 0.f;
  unsigned short hi = f2bf(v);
  unsigned short lo = f2bf(v - bf2f(hi));
  w1h[e] = hi;
  w1l[e] = lo;
}

// bf16 convert of W2 [D][K2] -> [D][K2P] (pad zeros)
__global__ __launch_bounds__(256) void w2conv_kernel(const float* __restrict__ W2,
                                                     unsigned short* __restrict__ w2b) {
  int e = blockIdx.x * 256 + threadIdx.x;
  int k = e % K2P, row = e / K2P;
  w2b[e] = (k < K2_) ? f2bf(W2[(size_t)row * K2_ + k]) : (unsigned short)0;
}

// gather h [B][N][H] bf16 -> hcomp [B][N][K2P] bf16
// 4 elems/thread, int4 idx loads, ushort4 stores.
__global__ __launch_bounds__(256) void hcompact_kernel(const unsigned short* __restrict__ h,
                                                       const int* __restrict__ idx2,
                                                       unsigned short* __restrict__ hcomp) {
  int bn = blockIdx.x;
  int b = bn >> 7;
  const int* idxb = idx2 + (size_t)b * LDI2;
  const unsigned short* hr = h + (size_t)bn * H_;
  unsigned short* o = hcomp + (size_t)bn * K2P;
  for (int j0 = threadIdx.x * 4; j0 < K2P; j0 += 1024) {
    ushort4v v;
    if (j0 < K2_) {                       // K2_ % 4 == 0: chunk fully valid
      int4 id = *(const int4*)&idxb[j0];
      v[0] = hr[id.x]; v[1] = hr[id.y]; v[2] = hr[id.z]; v[3] = hr[id.w];
    } else {
      v[0] = 0; v[1] = 0; v[2] = 0; v[3] = 0;
    }
    *(ushort4v*)&o[j0] = v;
  }
}

// ---------------------------------------------------------------------------
// GEMM1: h = relu(xc * W1^T + b1) via bf16x3 split MFMA; bf16 h store + fused
// scores2 epilogue.
// CLUSTER24 MFMAs interleaved across rows/passes so same-accumulator MFMAs
// are >= 8 apart (was back-to-back). Per acc element the add order is still
// hh -> hl -> lh -> h is bitwise identical.
// ---------------------------------------------------------------------------
#define MF1(d, a, b) d = __builtin_amdgcn_mfma_f32_16x16x32_bf16(a, b, d, 0, 0, 0)

#define CLUSTER24(i0, A0H, A0L, A1H, A1L) \
  __builtin_amdgcn_s_setprio(1); \
  { _Pragma("unroll") \
    for (int j = 0; j < 4; ++j) MF1(acc[i0][j], A0H, bh[j]); \
    _Pragma("unroll") \
    for (int j = 0; j < 4; ++j) MF1(acc[(i0) + 1][j], A1H, bh[j]); \
    _Pragma("unroll") \
    for (int j = 0; j < 4; ++j) MF1(acc[i0][j], A0H, bl[j]); \
    _Pragma("unroll") \
    for (int j = 0; j < 4; ++j) MF1(acc[(i0) + 1][j], A1H, bl[j]); \
    _Pragma("unroll") \
    for (int j = 0; j < 4; ++j) MF1(acc[i0][j], A0L, bh[j]); \
    _Pragma("unroll") \
    for (int j = 0; j < 4; ++j) MF1(acc[(i0) + 1][j], A1L, bh[j]); \
  } \
  __builtin_amdgcn_s_setprio(0);

__global__ __launch_bounds__(512, 2) void gemm1_kernel(
    const unsigned short* __restrict__ xch, const unsigned short* __restrict__ xcl,
    const unsigned short* __restrict__ w1h, const unsigned short* __restrict__ w1l,
    const float* __restrict__ b1, const float* __restrict__ ws2,
    unsigned short* __restrict__ h, float* __restrict__ scores2) {
  const int hc0 = blockIdx.x * 256;
  const int b0 = blockIdx.y * 2;
  const int t = threadIdx.x, w = t >> 6, lane = t & 63;
  const int ml = lane & 15, qd = lane >> 4;
  const int wm = w >> 2, wn = w & 3;   // 2(m) x 4(n) wave grid

  __shared__ unsigned short Ah[2][8192], Al[2][8192], Bh[2][8192], Bl[2][8192];

  floatx4 acc[8][4] = {};

  const unsigned short* Abh = xch + (size_t)b0 * N_ * K1P;
  const unsigned short* Abl = xcl + (size_t)b0 * N_ * K1P;
  const unsigned short* Bbh = w1h + (size_t)hc0 * K1P;
  const unsigned short* Bbl = w1l + (size_t)hc0 * K1P;

  const int c0 = w * 64 + lane, c1 = c0 + 512;
  const size_t off0 = (size_t)(((c0 >> 6) << 4) | (c0 & 15)) * K1P + (size_t)(((c0 >> 4) & 3) * 8);
  const size_t off1 = (size_t)(((c1 >> 6) << 4) | (c1 & 15)) * K1P + (size_t)(((c1 >> 4) & 3) * 8);
  const int lb0 = (w * 64) * 8;
  const int lb1 = (512 + w * 64) * 8;

  auto aof = [&](int i) { return ((wm * 8 + i) * 64 + qd * 16 + ml) * 8; };

  GL16(Abh + off0, &Ah[0][lb0]); GL16(Abh + off1, &Ah[0][lb1]);
  GL16(Abl + off0, &Al[0][lb0]); GL16(Abl + off1, &Al[0][lb1]);
  GL16(Bbh + off0, &Bh[0][lb0]); GL16(Bbh + off1, &Bh[0][lb1]);
  GL16(Bbl + off0, &Bl[0][lb0]); GL16(Bbl + off1, &Bl[0][lb1]);

  for (int kt = 0; kt < KT1; ++kt) {
    const int cur = kt & 1, nxt = cur ^ 1;
    const size_t kk = (size_t)(kt + 1) * 32;
    const bool stg = (kt + 1 < KT1);

    if (stg) { GL16(Bbh + off0 + kk, &Bh[nxt][lb0]); GL16(Bbh + off1 + kk, &Bh[nxt][lb1]); }
    if (stg) asm volatile("s_waitcnt vmcnt(2)" ::: "memory");
    else     asm volatile("s_waitcnt vmcnt(0)" ::: "memory");
    __builtin_amdgcn_s_barrier();

    bf16x8 bh[4], bl[4];
#pragma unroll
    for (int j = 0; j < 4; ++j) {
      const int bo = ((wn * 4 + j) * 64 + qd * 16 + ml) * 8;
      bh[j] = *(const bf16x8*)&Bh[cur][bo];
      bl[j] = *(const bf16x8*)&Bl[cur][bo];
    }
    bf16x8 a0h = *(const bf16x8*)&Ah[cur][aof(0)];
    bf16x8 a0l = *(const bf16x8*)&Al[cur][aof(0)];
    bf16x8 a1h = *(const bf16x8*)&Ah[cur][aof(1)];
    bf16x8 a1l = *(const bf16x8*)&Al[cur][aof(1)];
    bf16x8 a2h = *(const bf16x8*)&Ah[cur][aof(2)];
    bf16x8 a2l = *(const bf16x8*)&Al[cur][aof(2)];
    bf16x8 a3h = *(const bf16x8*)&Ah[cur][aof(3)];
    bf16x8 a3l = *(const bf16x8*)&Al[cur][aof(3)];
    if (stg) { GL16(Bbl + off0 + kk, &Bl[nxt][lb0]); GL16(Bbl + off1 + kk, &Bl[nxt][lb1]); }
    __builtin_amdgcn_sched_barrier(0);
    CLUSTER24(0, a0h, a0l, a1h, a1l)
    __builtin_amdgcn_s_barrier();

    bf16x8 a4h = *(const bf16x8*)&Ah[cur][aof(4)];
    bf16x8 a4l = *(const bf16x8*)&Al[cur][aof(4)];
    bf16x8 a5h = *(const bf16x8*)&Ah[cur][aof(5)];
    bf16x8 a5l = *(const bf16x8*)&Al[cur][aof(5)];
    if (stg) { GL16(Abh + off0 + kk, &Ah[nxt][lb0]); GL16(Abh + off1 + kk, &Ah[nxt][lb1]); }
    __builtin_amdgcn_sched_barrier(0);
    CLUSTER24(2, a2h, a2l, a3h, a3l)
    __builtin_amdgcn_s_barrier();

    bf16x8 a6h = *(const bf16x8*)&Ah[cur][aof(6)];
    bf16x8 a6l = *(const bf16x8*)&Al[cur][aof(6)];
    bf16x8 a7h = *(const bf16x8*)&Ah[cur][aof(7)];
    bf16x8 a7l = *(const bf16x8*)&Al[cur][aof(7)];
    if (stg) { GL16(Abl + off0 + kk, &Al[nxt][lb0]); GL16(Abl + off1 + kk, &Al[nxt][lb1]); }
    __builtin_amdgcn_sched_barrier(0);
    CLUSTER24(4, a4h, a4l, a5h, a5l)
    __builtin_amdgcn_s_barrier();

    __builtin_amdgcn_sched_barrier(0);
    CLUSTER24(6, a6h, a6l, a7h, a7l)
    __builtin_amdgcn_s_barrier();
  }

  const int bb = b0 + wm;
  float bias[4];
#pragma unroll
  for (int j = 0; j < 4; ++j) bias[j] = b1[hc0 + wn * 64 + j * 16 + ml];
  float sc[4] = {0.f, 0.f, 0.f, 0.f};
#pragma unroll
  for (int i = 0; i < 8; ++i) {
#pragma unroll
    for (int r = 0; r < 4; ++r) {
      const int n = i * 16 + qd * 4 + r;
      const float wsn = ws2[n];
      unsigned short* hp = h + ((size_t)(bb * N_ + n)) * H_ + hc0 + wn * 64;
#pragma unroll
      for (int j = 0; j < 4; ++j) {
        float v = acc[i][j][r] + bias[j];
        v = fmaxf(v, 0.f);
        hp[j * 16 + ml] = f2bf(v);
        sc[j] += v * wsn;
      }
    }
  }
#pragma unroll
  for (int j = 0; j < 4; ++j) {
    sc[j] += __shfl_xor(sc[j], 16);
    sc[j] += __shfl_xor(sc[j], 32);
  }
  if (lane < 16) {
#pragma unroll
    for (int j = 0; j < 4; ++j)
      scores2[(size_t)bb * H_ + hc0 + wn * 64 + j * 16 + lane] = sc[j];
  }
}

// ---------------------------------------------------------------------------
// GEMM2: out = hcomp * W2^T + b2. BK=64, 256x256 tile, 8 waves,
// double-buffered 128 KiB LDS, counted vmcnt(2) at boundaries only.
// ---------------------------------------------------------------------------
#define MF2(d, a, b) d = __builtin_amdgcn_mfma_f32_16x16x32_bf16(a, b, d, 0, 0, 0)

#define CL16(i0, A0, A1, A2r, A3, BB) \
  __builtin_amdgcn_s_setprio(1); \
  { _Pragma("unroll") \
    for (int j = 0; j < 4; ++j) { \
      MF2(acc[(i0)][j], A0, BB[j]); \
      MF2(acc[(i0) + 1][j], A1, BB[j]); \
      MF2(acc[(i0) + 2][j], A2r, BB[j]); \
      MF2(acc[(i0) + 3][j], A3, BB[j]); \
    } } \
  __builtin_amdgcn_s_setprio(0);

__global__ __launch_bounds__(512, 2) void gemm2_kernel(
    const unsigned short* __restrict__ hcomp, const unsigned short* __restrict__ w2b,
    const float* __restrict__ b2, float* __restrict__ out) {
  const int d0 = blockIdx.x * 256;
  const int b0 = blockIdx.y * 2;
  const int t = threadIdx.x, w = t >> 6, lane = t & 63;
  const int ml = lane & 15, qd = lane >> 4;
  const int wm = w >> 2, wn = w & 3;   // 2(m) x 4(n) wave grid

  __shared__ unsigned short As[2][2][8192], Bs[2][2][8192];   // 128 KiB

  floatx4 acc[8][4] = {};

  const unsigned short* Ab = hcomp + (size_t)b0 * N_ * K2P;   // 256 rows (2 batches)
  const unsigned short* Bb = w2b + (size_t)d0 * K2P;          // 256 d rows

  const int c0 = w * 64 + lane, c1 = c0 + 512;
  const size_t off0 = (size_t)(((c0 >> 6) << 4) | (c0 & 15)) * K2P + (size_t)(((c0 >> 4) & 3) * 8);
  const size_t off1 = (size_t)(((c1 >> 6) << 4) | (c1 & 15)) * K2P + (size_t)(((c1 >> 4) & 3) * 8);
  const int lb0 = (w * 64) * 8, lb1 = (512 + w * 64) * 8;

  auto aof = [&](int i) { return ((wm * 8 + i) * 64 + qd * 16 + ml) * 8; };
  auto bof = [&](int j) { return ((wn * 4 + j) * 64 + qd * 16 + ml) * 8; };

  // prologue: stage iter 0 fully (A h0/h1, B h0/h1 = 8 loads/wave)
  GL16(Ab + off0,      &As[0][0][lb0]); GL16(Ab + off1,      &As[0][0][lb1]);
  GL16(Ab + off0 + 32, &As[0][1][lb0]); GL16(Ab + off1 + 32, &As[0][1][lb1]);
  GL16(Bb + off0,      &Bs[0][0][lb0]); GL16(Bb + off1,      &Bs[0][0][lb1]);
  GL16(Bb + off0 + 32, &Bs[0][1][lb0]); GL16(Bb + off1 + 32, &Bs[0][1][lb1]);

  for (int kt = 0; kt < KT2D; ++kt) {
    const int cur = kt & 1, nxt = cur ^ 1;
    const size_t kk = (size_t)(kt + 1) * 64;
    const bool stg = (kt + 1 < KT2D);

    // boundary: prefetch A-h0(next); counted wait; barrier
    if (stg) { GL16(Ab + off0 + kk, &As[nxt][0][lb0]); GL16(Ab + off1 + kk, &As[nxt][0][lb1]); }
    if (stg) asm volatile("s_waitcnt vmcnt(2)" ::: "memory");
    else     asm volatile("s_waitcnt vmcnt(0)" ::: "memory");
    __builtin_amdgcn_s_barrier();

    // W0: read b(h0), a0-7(h0); stage A-h1(next); MFMA rows0-3 @ h0
    bf16x8 bh0[4];
#pragma unroll
    for (int j = 0; j < 4; ++j) bh0[j] = *(const bf16x8*)&Bs[cur][0][bof(j)];
    bf16x8 a0 = *(const bf16x8*)&As[cur][0][aof(0)];
    bf16x8 a1 = *(const bf16x8*)&As[cur][0][aof(1)];
    bf16x8 a2 = *(const bf16x8*)&As[cur][0][aof(2)];
    bf16x8 a3 = *(const bf16x8*)&As[cur][0][aof(3)];
    bf16x8 a4 = *(const bf16x8*)&As[cur][0][aof(4)];
    bf16x8 a5 = *(const bf16x8*)&As[cur][0][aof(5)];
    bf16x8 a6 = *(const bf16x8*)&As[cur][0][aof(6)];
    bf16x8 a7 = *(const bf16x8*)&As[cur][0][aof(7)];
    if (stg) { GL16(Ab + off0 + kk + 32, &As[nxt][1][lb0]); GL16(Ab + off1 + kk + 32, &As[nxt][1][lb1]); }
    __builtin_amdgcn_sched_barrier(0);
    CL16(0, a0, a1, a2, a3, bh0)
    __builtin_amdgcn_s_barrier();

    // W1: read b(h1), e0-3(h1); stage B-h0(next); MFMA rows4-7 @ h0
    bf16x8 bh1[4];
#pragma unroll
    for (int j = 0; j < 4; ++j) bh1[j] = *(const bf16x8*)&Bs[cur][1][bof(j)];
    bf16x8 e0 = *(const bf16x8*)&As[cur][1][aof(0)];
    bf16x8 e1 = *(const bf16x8*)&As[cur][1][aof(1)];
    bf16x8 e2 = *(const bf16x8*)&As[cur][1][aof(2)];
    bf16x8 e3 = *(const bf16x8*)&As[cur][1][aof(3)];
    if (stg) { GL16(Bb + off0 + kk, &Bs[nxt][0][lb0]); GL16(Bb + off1 + kk, &Bs[nxt][0][lb1]); }
    __builtin_amdgcn_sched_barrier(0);
    CL16(4, a4, a5, a6, a7, bh0)
    __builtin_amdgcn_s_barrier();

    // W2: read e4-7(h1); stage B-h1(next); MFMA rows0-3 @ h1
    bf16x8 e4 = *(const bf16x8*)&As[cur][1][aof(4)];
    bf16x8 e5 = *(const bf16x8*)&As[cur][1][aof(5)];
    bf16x8 e6 = *(const bf16x8*)&As[cur][1][aof(6)];
    bf16x8 e7 = *(const bf16x8*)&As[cur][1][aof(7)];
    if (stg) { GL16(Bb + off0 + kk + 32, &Bs[nxt][1][lb0]); GL16(Bb + off1 + kk + 32, &Bs[nxt][1][lb1]); }
    __builtin_amdgcn_sched_barrier(0);
    CL16(0, e0, e1, e2, e3, bh1)
    __builtin_amdgcn_s_barrier();

    // W3: MFMA rows4-7 @ h1
    __builtin_amdgcn_sched_barrier(0);
    CL16(4, e4, e5, e6, e7, bh1)
    __builtin_amdgcn_s_barrier();
  }

  // epilogue: bias + fp32 store; wave wm owns batch b0+wm, all 128 n-rows
  const int bb = b0 + wm;
  float bias[4];
#pragma unroll
  for (int j = 0; j < 4; ++j) bias[j] = b2[d0 + wn * 64 + j * 16 + ml];
#pragma unroll
  for (int i = 0; i < 8; ++i) {
#pragma unroll
    for (int r = 0; r < 4; ++r) {
      const int n = i * 16 + qd * 4 + r;
      float* op = out + ((size_t)(bb * N_ + n)) * D_ + d0 + wn * 64;
#pragma unroll
      for (int j = 0; j < 4; ++j)
        op[j * 16 + ml] = acc[i][j][r] + bias[j];
    }
  }
}

// ---------------------------------------------------------------------------
extern "C" void kernel_launch(void* const* d_in, const int* in_sizes, int n_in,
                              void* d_out, int out_size, void* d_ws, size_t ws_size,
                              hipStream_t stream) {
  (void)in_sizes; (void)n_in; (void)out_size; (void)ws_size;
  const float* x   = (const float*)d_in[0];
  const float* ws1 = (const float*)d_in[1];
  const float* W1  = (const float*)d_in[3];
  const float* b1  = (const float*)d_in[4];
  const float* ws2 = (const float*)d_in[5];
  const float* W2  = (const float*)d_in[7];
  const float* b2  = (const float*)d_in[8];
  float* out = (float*)d_out;

  char* p = (char*)d_ws;
  auto alloc = [&](size_t bytes) {
    char* r = p;
    p += (bytes + 255) & ~(size_t)255;
    return r;
  };
  float* scores1 = (float*)alloc((size_t)B_ * D_ * sizeof(float));
  int*   idx1    = (int*)  alloc((size_t)B_ * LDI1 * sizeof(int));
  float* scores2 = (float*)alloc((size_t)B_ * H_ * sizeof(float));
  int*   idx2    = (int*)  alloc((size_t)B_ * LDI2 * sizeof(int));
  unsigned short* w1h = (unsigned short*)alloc((size_t)H_ * K1P * sizeof(short));
  unsigned short* w1l = (unsigned short*)alloc((size_t)H_ * K1P * sizeof(short));
  unsigned short* w2b = (unsigned short*)alloc((size_t)D_ * K2P * sizeof(short));
  unsigned short* h   = (unsigned short*)alloc((size_t)B_ * N_ * H_ * sizeof(short));
  // region shared by {xch, xcl} (live through gemm1) and hcomp (live after)
  size_t xc_bytes    = (size_t)B_ * N_ * K1P * sizeof(short);   // 54.5 MB each
  size_t hcomp_bytes = (size_t)B_ * N_ * K2P * sizeof(short);   // 218 MB
  char* region = alloc(hcomp_bytes > 2 * xc_bytes ? hcomp_bytes : 2 * xc_bytes);
  unsigned short* xch   = (unsigned short*)region;
  unsigned short* xcl   = (unsigned short*)(region + xc_bytes);
  unsigned short* hcomp = (unsigned short*)region;  // aliases xc after gemm1 (stream-ordered)

  scores1_kernel<<<B_, 1024, 0, stream>>>(x, ws1, scores1);
  topk_kernel<<<B_, 256, 0, stream>>>(scores1, D_, K1_, LDI1, idx1);
  xprep_kernel<<<B_ * N_, 256, 0, stream>>>(x, idx1, xch, xcl);
  w1split_kernel<<<(H_ * K1P) / 256, 256, 0, stream>>>(W1, w1h, w1l);
  w2conv_kernel<<<(D_ * K2P) / 256, 256, 0, stream>>>(W2, w2b);
  gemm1_kernel<<<dim3(H_ / 256, B_ / 2), 512, 0, stream>>>(xch, xcl, w1h, w1l, b1, ws2, h, scores2);
  topk_kernel<<<B_, 256, 0, stream>>>(scores2, H_, K2_, LDI2, idx2);
  hcompact_kernel<<<B_ * N_, 256, 0, stream>>>(h, idx2, hcomp);
  gemm2_kernel<<<dim3(D_ / 256, B_ / 2), 512, 0, stream>>>(hcomp, w2b, b2, out);
}